// Round 11
// baseline (735.275 us; speedup 1.0000x reference)
//
#include <hip/hip_runtime.h>
#include <hip/hip_bf16.h>
#include <stdint.h>

using f16 = _Float16;
typedef _Float16 f16x8 __attribute__((ext_vector_type(8)));
typedef float f32x4 __attribute__((ext_vector_type(4)));

static constexpr int HW = 4096;        // H*W
static constexpr int CC = 256;         // channels
static constexpr int ROWS = 131072;    // B*H*W
static constexpr int ACH = 4;          // attention-phase chunks
static constexpr int AROWS = ROWS / ACH;      // 32768 rows / chunk
static constexpr int CWINS = AROWS / 64;      // 512 windows / chunk
static constexpr int SSH = 4;          // shift

// workspace layout (bytes)
static constexpr size_t OFF_WQ = 0;                               // qkv_w f16  768*256
static constexpr size_t OFF_WP = OFF_WQ + (size_t)768*256*2;      // proj_w f16 256*256
static constexpr size_t OFF_W1 = OFF_WP + (size_t)256*256*2;      // fc1_w f16  1024*256
static constexpr size_t OFF_W2 = OFF_W1 + (size_t)1024*256*2;     // fc2_w f16  256*1024
static constexpr size_t OFF_R1 = OFF_W2 + (size_t)256*1024*2;     // 67,108,864 B region
static constexpr size_t OFF_R2 = OFF_R1 + (size_t)ROWS*CC*2;      // 67,108,864 B region
// R1: AW full (131072x256 f16). R2: hwin chunk + Q + K + V -> then m_in full.

__device__ __forceinline__ void gload16(void* lds, const void* g) {
    __builtin_amdgcn_global_load_lds(
        (const __attribute__((address_space(1))) unsigned int*)g,
        (__attribute__((address_space(3))) unsigned int*)lds, 16, 0, 0);
}

__global__ void k_cvt(const float* __restrict__ s, f16* __restrict__ d, int n) {
    int i = blockIdx.x * 256 + threadIdx.x;
    if (i < n) d[i] = (f16)s[i];
}

// LayerNorm over C=256, dest row (windowed+rolled) gathers from source row of x.
__global__ __launch_bounds__(256) void k_ln(const float* __restrict__ x,
                                            const float* __restrict__ g,
                                            const float* __restrict__ be,
                                            f16* __restrict__ dst, int rowbase) {
    int lrow = blockIdx.x * 4 + (threadIdx.x >> 6);
    int grow = rowbase + lrow;
    int lane = threadIdx.x & 63;
    int n = grow & 63, win = (grow >> 6) & 63, b = grow >> 12;
    int hh  = ((win >> 3) << 3) | (n >> 3);
    int wwc = ((win & 7) << 3) | (n & 7);
    int ho = (hh + SSH) & 63, wo = (wwc + SSH) & 63;
    size_t srow = (size_t)b * HW + ho * 64 + wo;
    float4 v = ((const float4*)(x + srow * CC))[lane];
    float s  = v.x + v.y + v.z + v.w;
    float s2 = v.x*v.x + v.y*v.y + v.z*v.z + v.w*v.w;
#pragma unroll
    for (int off = 32; off; off >>= 1) { s += __shfl_xor(s, off); s2 += __shfl_xor(s2, off); }
    float mean = s * (1.f/256.f);
    float rstd = rsqrtf(s2 * (1.f/256.f) - mean*mean + 1e-5f);
    float4 gv = ((const float4*)g)[lane];
    float4 bv = ((const float4*)be)[lane];
    f16 ob[4];
    ob[0] = (f16)((v.x-mean)*rstd*gv.x + bv.x);
    ob[1] = (f16)((v.y-mean)*rstd*gv.y + bv.y);
    ob[2] = (f16)((v.z-mean)*rstd*gv.z + bv.z);
    ob[3] = (f16)((v.w-mean)*rstd*gv.w + bv.w);
    *(uint2*)(dst + (size_t)lrow * CC + lane * 4) = *(const uint2*)ob;
}

// QKV GEMM: 128x128 tile, BK=32, 2-phase double-buffer.
// FRAGMENT-MAJOR LDS: chunk c (16 rows x 32 k) stored so lane l's fragment is
// at chunk_base + l*16B -> all ds_read_b128 conflict-free. Global source per
// lane: row = c*16 + (l&15), col = k0 + (l>>4)*8 (16x64B segments, same
// coalescing as row-major staging).
__global__ __launch_bounds__(256) void k_qkv(const f16* __restrict__ A,
                                             const f16* __restrict__ Wt,
                                             const float* __restrict__ bias,
                                             f16* __restrict__ q, f16* __restrict__ kk,
                                             f16* __restrict__ vv) {
    __shared__ f16 As[2][128 * 32];
    __shared__ f16 Bs[2][128 * 32];
    const int tid = threadIdx.x;
    const int m0 = blockIdx.x * 128, n0 = blockIdx.y * 128;
    const int wave = tid >> 6, lane = tid & 63;
    const int wm = (wave >> 1) * 64, wn = (wave & 1) * 64;
    const int lr = lane & 15, kq = lane >> 4;

    auto stage = [&](int b, int k0) {
#pragma unroll
        for (int t = 0; t < 2; t++) {
            int c = wave * 2 + t;                    // chunk 0..7
            int row = c * 16 + lr;
            gload16(&As[b][c * 512], &A [(size_t)(m0 + row) * CC + k0 + kq * 8]);
            gload16(&Bs[b][c * 512], &Wt[(size_t)(n0 + row) * CC + k0 + kq * 8]);
        }
    };

    f32x4 acc[4][4];
#pragma unroll
    for (int i = 0; i < 4; i++)
#pragma unroll
        for (int j = 0; j < 4; j++) acc[i][j] = f32x4{0.f, 0.f, 0.f, 0.f};

    stage(0, 0);
    __syncthreads();
    for (int s = 0; s < 8; s++) {
        int cur = s & 1;
        if (s + 1 < 8) stage(cur ^ 1, (s + 1) * 32);
        f16x8 af[4], bfv[4];
#pragma unroll
        for (int i = 0; i < 4; i++) {
            af[i]  = *(const f16x8*)(&As[cur][((wave >> 1) * 4 + i) * 512 + lane * 8]);
            bfv[i] = *(const f16x8*)(&Bs[cur][((wave & 1) * 4 + i) * 512 + lane * 8]);
        }
#pragma unroll
        for (int mi = 0; mi < 4; mi++)
#pragma unroll
            for (int ni = 0; ni < 4; ni++)
                acc[mi][ni] = __builtin_amdgcn_mfma_f32_16x16x32_f16(af[mi], bfv[ni], acc[mi][ni], 0, 0, 0);
        __syncthreads();
    }

#pragma unroll
    for (int mi = 0; mi < 4; mi++)
#pragma unroll
        for (int ni = 0; ni < 4; ni++)
#pragma unroll
            for (int j = 0; j < 4; j++) {
                int lrow = m0 + wm + mi * 16 + kq * 4 + j;   // C/D: row=(lane>>4)*4+j
                int gcol = n0 + wn + ni * 16 + lr;           //      col=lane&15
                float val = acc[mi][ni][j] + bias[gcol];
                int s = gcol >> 8, h2 = (gcol >> 5) & 7, d = gcol & 31;
                if (s == 0) val *= 0.1767766952966369f;  // HD^-0.5
                f16* dst = (s == 0) ? q : (s == 1 ? kk : vv);
                int winl = lrow >> 6, n = lrow & 63;
                dst[(((size_t)winl * 8 + h2) * 64 + n) * 32 + d] = (f16)val;
            }
}

// proj GEMM, 64 rows x 256 cols/block, fragment-major LDS staging,
// fused un-shift+residual->out + LN2->m_out.
__global__ __launch_bounds__(256, 2) void k_proj(const f16* __restrict__ A,
                                                 const f16* __restrict__ Wt,
                                                 const float* __restrict__ bias,
                                                 const float* __restrict__ x_in,
                                                 float* __restrict__ outf,
                                                 f16* __restrict__ m_out,
                                                 const float* __restrict__ g2,
                                                 const float* __restrict__ b2) {
    __shared__ f16 As[2][64 * 32];
    __shared__ f16 Bs[2][256 * 32];
    __shared__ float rsum[4][64];
    __shared__ float rsq[4][64];
    const int tid = threadIdx.x;
    const int m0 = blockIdx.x * 64;
    const int wave = tid >> 6, lane = tid & 63;
    const int lr = lane & 15, kq = lane >> 4;

    auto stage = [&](int b, int k0) {
        gload16(&As[b][wave * 512], &A[(size_t)(m0 + wave * 16 + lr) * CC + k0 + kq * 8]);
#pragma unroll
        for (int r = 0; r < 4; r++) {
            int c = wave * 4 + r;                    // B chunk 0..15 (rows c*16+lr)
            gload16(&Bs[b][c * 512], &Wt[(size_t)(c * 16 + lr) * CC + k0 + kq * 8]);
        }
    };

    f32x4 acc[4][4];
#pragma unroll
    for (int i = 0; i < 4; i++)
#pragma unroll
        for (int j = 0; j < 4; j++) acc[i][j] = f32x4{0.f, 0.f, 0.f, 0.f};

    stage(0, 0);
    __syncthreads();
    for (int s = 0; s < 8; s++) {
        int cur = s & 1;
        if (s + 1 < 8) stage(cur ^ 1, (s + 1) * 32);
        f16x8 af[4], bfv[4];
#pragma unroll
        for (int i = 0; i < 4; i++) {
            af[i]  = *(const f16x8*)(&As[cur][i * 512 + lane * 8]);
            bfv[i] = *(const f16x8*)(&Bs[cur][(wave * 4 + i) * 512 + lane * 8]);
        }
#pragma unroll
        for (int mi = 0; mi < 4; mi++)
#pragma unroll
            for (int ni = 0; ni < 4; ni++)
                acc[mi][ni] = __builtin_amdgcn_mfma_f32_16x16x32_f16(af[mi], bfv[ni], acc[mi][ni], 0, 0, 0);
        __syncthreads();
    }

    // ---- epilogue: x2 = proj + bias + shortcut (per un-shift scatter) ----
    int srows[4][4];
#pragma unroll
    for (int mi = 0; mi < 4; mi++)
#pragma unroll
        for (int j = 0; j < 4; j++) {
            int row = m0 + mi * 16 + kq * 4 + j;       // windowed-order global row
            int n = row & 63, win = (row >> 6) & 63, b = row >> 12;
            int hh  = ((win >> 3) << 3) | (n >> 3);
            int wwc = ((win & 7) << 3) | (n & 7);
            int ho = (hh + SSH) & 63, wo = (wwc + SSH) & 63;
            srows[mi][j] = b * HW + ho * 64 + wo;
        }
    float bv[4], gv[4], b2v[4];
#pragma unroll
    for (int ni = 0; ni < 4; ni++) {
        int gcol = wave * 64 + ni * 16 + lr;
        bv[ni] = bias[gcol]; gv[ni] = g2[gcol]; b2v[ni] = b2[gcol];
    }
    float ps[4][4], qs[4][4];
#pragma unroll
    for (int mi = 0; mi < 4; mi++)
#pragma unroll
        for (int j = 0; j < 4; j++) { ps[mi][j] = 0.f; qs[mi][j] = 0.f; }
#pragma unroll
    for (int mi = 0; mi < 4; mi++)
#pragma unroll
        for (int ni = 0; ni < 4; ni++) {
            int gcol = wave * 64 + ni * 16 + lr;
#pragma unroll
            for (int j = 0; j < 4; j++) {
                size_t idx = (size_t)srows[mi][j] * CC + gcol;
                float v = acc[mi][ni][j] + bv[ni] + x_in[idx];
                acc[mi][ni][j] = v;
                outf[idx] = v;
                ps[mi][j] += v; qs[mi][j] += v * v;
            }
        }
#pragma unroll
    for (int off = 1; off < 16; off <<= 1)
#pragma unroll
        for (int mi = 0; mi < 4; mi++)
#pragma unroll
            for (int j = 0; j < 4; j++) {
                ps[mi][j] += __shfl_xor(ps[mi][j], off);
                qs[mi][j] += __shfl_xor(qs[mi][j], off);
            }
    if (lr == 0) {
#pragma unroll
        for (int mi = 0; mi < 4; mi++)
#pragma unroll
            for (int j = 0; j < 4; j++) {
                int rl = mi * 16 + kq * 4 + j;
                rsum[wave][rl] = ps[mi][j];
                rsq[wave][rl]  = qs[mi][j];
            }
    }
    __syncthreads();
    float mean_a[4][4], rstd_a[4][4];
#pragma unroll
    for (int mi = 0; mi < 4; mi++)
#pragma unroll
        for (int j = 0; j < 4; j++) {
            int rl = mi * 16 + kq * 4 + j;
            float s  = rsum[0][rl] + rsum[1][rl] + rsum[2][rl] + rsum[3][rl];
            float s2 = rsq[0][rl] + rsq[1][rl] + rsq[2][rl] + rsq[3][rl];
            float mean = s * (1.f/256.f);
            float var  = s2 * (1.f/256.f) - mean * mean;
            mean_a[mi][j] = mean;
            rstd_a[mi][j] = rsqrtf(var + 1e-5f);
        }
#pragma unroll
    for (int mi = 0; mi < 4; mi++)
#pragma unroll
        for (int ni = 0; ni < 4; ni++) {
            int gcol = wave * 64 + ni * 16 + lr;
#pragma unroll
            for (int j = 0; j < 4; j++) {
                float m = (acc[mi][ni][j] - mean_a[mi][j]) * rstd_a[mi][j] * gv[ni] + b2v[ni];
                m_out[(size_t)srows[mi][j] * CC + gcol] = (f16)m;
            }
        }
}

// Fused MLP: out += fc2(gelu(fc1(m_in))); fragment-major LDS everywhere:
// - As/Bs1/Bs2 staged chunk-major (lane*16) -> conflict-free ds_read_b128
// - h handoff fragment-major for fc2: fc1-swapped acc writes land as 64
//   contiguous uint2/wave (conflict-free); fc2 reads h at lane*16.
// Cheap GELU: v*rcp(1+exp(v*(e1+e2*v^2))) via v_rcp (saves precise-div chain).
__global__ __launch_bounds__(256) void k_mlp2(const f16* __restrict__ A,
                                              const f16* __restrict__ w1,
                                              const f16* __restrict__ w2,
                                              const float* __restrict__ fb1,
                                              const float* __restrict__ fb2,
                                              float* __restrict__ out) {
    __shared__ char sm[49152];
    char* hbuf = sm;                 // 16KB fragment-major h: [ks][mi][lane*16]
    char* S    = sm + 16384;         // 32KB: fc1 (As 8K + Bs1 16K) / fc2 Bs2 32K
    f16* As  = (f16*)S;              // [2][4 chunks * 512]
    f16* Bs1 = (f16*)(S + 8192);     // [2][8 chunks * 512]
    f16* Bs2 = (f16*)S;              // [2][16 chunks * 512]
    const int tid = threadIdx.x, wave = tid >> 6, lane = tid & 63;
    const int lr = lane & 15, kq = lane >> 4;
    const int m0 = blockIdx.x * 64;

    f32x4 acc2[4][4];
#pragma unroll
    for (int i = 0; i < 4; i++)
#pragma unroll
        for (int j = 0; j < 4; j++) acc2[i][j] = f32x4{0.f, 0.f, 0.f, 0.f};

    for (int nb = 0; nb < 8; nb++) {
        auto stage1 = [&](int b, int k0) {
            gload16(&As[b * 2048 + wave * 512],
                    &A[(size_t)(m0 + wave * 16 + lr) * CC + k0 + kq * 8]);
#pragma unroll
            for (int t = 0; t < 2; t++) {
                int c = wave * 2 + t;        // w1 chunk 0..7 (rows c*16+lr of slice)
                gload16(&Bs1[b * 4096 + c * 512],
                        &w1[(size_t)(nb * 128 + c * 16 + lr) * CC + k0 + kq * 8]);
            }
        };
        // ---- fc1 slice (swapped): acc1[hid frags][q frags] ----
        f32x4 acc1[2][4];
#pragma unroll
        for (int i = 0; i < 2; i++)
#pragma unroll
            for (int j = 0; j < 4; j++) acc1[i][j] = f32x4{0.f, 0.f, 0.f, 0.f};
        stage1(0, 0);
        __syncthreads();
#pragma unroll
        for (int ks = 0; ks < 8; ks++) {
            int cur = ks & 1;
            if (ks + 1 < 8) stage1(cur ^ 1, (ks + 1) * 32);
            f16x8 aw1[2], bx[4];
#pragma unroll
            for (int hi = 0; hi < 2; hi++)
                aw1[hi] = *(const f16x8*)(&Bs1[cur * 4096 + (wave * 2 + hi) * 512 + lane * 8]);
#pragma unroll
            for (int qi = 0; qi < 4; qi++)
                bx[qi] = *(const f16x8*)(&As[cur * 2048 + qi * 512 + lane * 8]);
#pragma unroll
            for (int hi = 0; hi < 2; hi++)
#pragma unroll
                for (int qi = 0; qi < 4; qi++)
                    acc1[hi][qi] = __builtin_amdgcn_mfma_f32_16x16x32_f16(
                        aw1[hi], bx[qi], acc1[hi][qi], 0, 0, 0);
            __syncthreads();
        }
        // ---- gelu -> h fragment-major (conflict-free uint2 writes) ----
        // element (q=qi*16+lr, hid=wave*32+hi*16+kq*4+j) ->
        // hbuf[wave*4096 + qi*1024 + (hi*2+(kq>>1))*256 + lr*16 + (kq&1)*8]
#pragma unroll
        for (int hi = 0; hi < 2; hi++) {
            float4 bb4 = *(const float4*)&fb1[nb * 128 + wave * 32 + hi * 16 + kq * 4];
            const float bb[4] = {bb4.x, bb4.y, bb4.z, bb4.w};
            const int dbase = wave * 4096 + (hi * 2 + (kq >> 1)) * 256 + lr * 16 + (kq & 1) * 8;
#pragma unroll
            for (int qi = 0; qi < 4; qi++) {
                f16 t4[4];
#pragma unroll
                for (int j = 0; j < 4; j++) {
                    float v = acc1[hi][qi][j] + bb[j];
                    // gelu(v) = v * sigmoid(2*0.7978845608*(v+0.044715 v^3))
                    float e = __expf(v * (-1.5957691216f - 0.07135482f * v * v));
                    t4[j] = (f16)(v * __builtin_amdgcn_rcpf(1.f + e));
                }
                *(uint2*)(hbuf + dbase + qi * 1024) = *(const uint2*)t4;
            }
        }
        auto stage2 = [&](int b, int k0) {
#pragma unroll
            for (int t = 0; t < 4; t++) {
                int c = wave * 4 + t;        // w2 chunk 0..15 (rows c*16+lr)
                gload16(&Bs2[b * 8192 + c * 512],
                        &w2[(size_t)(c * 16 + lr) * 1024 + nb * 128 + k0 + kq * 8]);
            }
        };
        stage2(0, 0);
        __syncthreads();     // h visible + Bs2[0] landed (barrier drains vmcnt)
        // ---- fc2 partial: acc2 += h @ w2_nb^T (all LDS reads lane*16) ----
#pragma unroll
        for (int ks = 0; ks < 4; ks++) {
            int cur = ks & 1;
            if (ks + 1 < 4) stage2(cur ^ 1, (ks + 1) * 32);
            f16x8 ah[4], bw[4];
#pragma unroll
            for (int mi = 0; mi < 4; mi++)
                ah[mi] = *(const f16x8*)(hbuf + ks * 4096 + mi * 1024 + lane * 16);
#pragma unroll
            for (int ni = 0; ni < 4; ni++)
                bw[ni] = *(const f16x8*)(&Bs2[cur * 8192 + (wave * 4 + ni) * 512 + lane * 8]);
#pragma unroll
            for (int mi = 0; mi < 4; mi++)
#pragma unroll
                for (int ni = 0; ni < 4; ni++)
                    acc2[mi][ni] = __builtin_amdgcn_mfma_f32_16x16x32_f16(
                        ah[mi], bw[ni], acc2[mi][ni], 0, 0, 0);
            __syncthreads();
        }
    }

    // ---- epilogue: out += acc2 + fb2 (coalesced 64B f32 segments) ----
#pragma unroll
    for (int mi = 0; mi < 4; mi++)
#pragma unroll
        for (int ni = 0; ni < 4; ni++)
#pragma unroll
            for (int j = 0; j < 4; j++) {
                int qrow = m0 + mi * 16 + kq * 4 + j;
                int oc = wave * 64 + ni * 16 + lr;
                size_t idx = (size_t)qrow * CC + oc;
                out[idx] = out[idx] + acc2[mi][ni][j] + fb2[oc];
            }
}

// MFMA attention: one wave per (window, head). S^T = mfma(K,Q); in-register
// softmax over keys; j-packed b64 swizzled LDS P-transpose; O^T = mfma(V^T, P);
// swizzled O-transpose -> 4 coalesced stores. 17.3KB LDS.
__global__ __launch_bounds__(64) void k_attn(const f16* __restrict__ q,
                                             const f16* __restrict__ kk,
                                             const f16* __restrict__ vv,
                                             const float* __restrict__ rpb,
                                             f16* __restrict__ aw, int winbase) {
    __shared__ char sm[17408];      // P[64][64] 8KB | VT[32][64] 4KB | O[64][32] 4KB | rl 900B
    float* rl = (float*)(sm + 16384);
    const int wl = blockIdx.x >> 3, h = blockIdx.x & 7;
    const int lane = threadIdx.x;
    const int lr = lane & 15, kq = lane >> 4;
    const size_t base = ((size_t)wl * 8 + h) * 2048;

    for (int i = lane; i < 225; i += 64) rl[i] = rpb[i * 8 + h];

    {
        f16 vr[32];
        const uint4* vs = (const uint4*)(vv + base + lane * 32);
#pragma unroll
        for (int c = 0; c < 4; c++) *(uint4*)&vr[c * 8] = vs[c];
#pragma unroll
        for (int d = 0; d < 32; d++)
            *(f16*)(sm + 8192 + d * 128 + ((lane * 2) ^ ((d & 7) << 4))) = vr[d];
    }

    f16x8 kf[4], qf[4];
#pragma unroll
    for (int t = 0; t < 4; t++) {
        kf[t] = *(const f16x8*)(kk + base + (size_t)(t * 16 + lr) * 32 + kq * 8);
        qf[t] = *(const f16x8*)(q  + base + (size_t)(t * 16 + lr) * 32 + kq * 8);
    }

    f32x4 st[4][4];
#pragma unroll
    for (int mi = 0; mi < 4; mi++)
#pragma unroll
        for (int ni = 0; ni < 4; ni++) st[mi][ni] = f32x4{0.f, 0.f, 0.f, 0.f};
#pragma unroll
    for (int mi = 0; mi < 4; mi++)
#pragma unroll
        for (int ni = 0; ni < 4; ni++)
            st[mi][ni] = __builtin_amdgcn_mfma_f32_16x16x32_f16(kf[mi], qf[ni], st[mi][ni], 0, 0, 0);

    __syncthreads();

    const int gwin = (winbase + wl) & 63;
    const int wh = gwin >> 3, ww = gwin & 7;
    int yq[4], xq[4], rq[4];
#pragma unroll
    for (int ni = 0; ni < 4; ni++) {
        int qq = ni * 16 + lr;
        yq[ni] = qq >> 3; xq[ni] = qq & 7;
        rq[ni] = ((wh < 7) ? 0 : ((yq[ni] < 4) ? 1 : 2)) * 3 +
                 ((ww < 7) ? 0 : ((xq[ni] < 4) ? 1 : 2));
    }
#pragma unroll
    for (int mi = 0; mi < 4; mi++)
#pragma unroll
        for (int j = 0; j < 4; j++) {
            int kt = mi * 16 + kq * 4 + j;
            int yk = kt >> 3, xk = kt & 7;
            int rk = ((wh < 7) ? 0 : ((yk < 4) ? 1 : 2)) * 3 +
                     ((ww < 7) ? 0 : ((xk < 4) ? 1 : 2));
#pragma unroll
            for (int ni = 0; ni < 4; ni++) {
                float b = rl[(yq[ni] - yk + 7) * 15 + (xq[ni] - xk + 7)];
                if (rq[ni] != rk) b -= 100.f;
                st[mi][ni][j] += b;
            }
        }

    float mx[4] = {-1e30f, -1e30f, -1e30f, -1e30f};
#pragma unroll
    for (int mi = 0; mi < 4; mi++)
#pragma unroll
        for (int ni = 0; ni < 4; ni++)
#pragma unroll
            for (int j = 0; j < 4; j++) mx[ni] = fmaxf(mx[ni], st[mi][ni][j]);
#pragma unroll
    for (int ni = 0; ni < 4; ni++) {
        mx[ni] = fmaxf(mx[ni], __shfl_xor(mx[ni], 16));
        mx[ni] = fmaxf(mx[ni], __shfl_xor(mx[ni], 32));
    }
    float sme[4] = {0.f, 0.f, 0.f, 0.f};
#pragma unroll
    for (int mi = 0; mi < 4; mi++)
#pragma unroll
        for (int ni = 0; ni < 4; ni++)
#pragma unroll
            for (int j = 0; j < 4; j++) {
                float e = __expf(st[mi][ni][j] - mx[ni]);
                st[mi][ni][j] = e;
                sme[ni] += e;
            }
#pragma unroll
    for (int ni = 0; ni < 4; ni++) {
        sme[ni] += __shfl_xor(sme[ni], 16);
        sme[ni] += __shfl_xor(sme[ni], 32);
    }
    float inv[4];
#pragma unroll
    for (int ni = 0; ni < 4; ni++) inv[ni] = 1.f / sme[ni];

#pragma unroll
    for (int mi = 0; mi < 4; mi++)
#pragma unroll
        for (int ni = 0; ni < 4; ni++) {
            f16 t4[4];
#pragma unroll
            for (int j = 0; j < 4; j++) t4[j] = (f16)st[mi][ni][j];
            int qq = ni * 16 + lr;
            *(uint2*)(sm + qq * 128 + ((mi * 32 + kq * 8) ^ ((qq & 7) << 4))) =
                *(const uint2*)t4;
        }
    __syncthreads();

    f32x4 oa[2][4];
#pragma unroll
    for (int mi2 = 0; mi2 < 2; mi2++)
#pragma unroll
        for (int ni = 0; ni < 4; ni++) oa[mi2][ni] = f32x4{0.f, 0.f, 0.f, 0.f};
#pragma unroll
    for (int ks = 0; ks < 2; ks++) {
        f16x8 va[2], pb[4];
#pragma unroll
        for (int mi2 = 0; mi2 < 2; mi2++) {
            int row = mi2 * 16 + lr;
            va[mi2] = *(const f16x8*)(sm + 8192 + row * 128 +
                                      ((ks * 64 + kq * 16) ^ ((row & 7) << 4)));
        }
#pragma unroll
        for (int ni = 0; ni < 4; ni++) {
            int qq = ni * 16 + lr;
            pb[ni] = *(const f16x8*)(sm + qq * 128 +
                                     ((ks * 64 + kq * 16) ^ ((qq & 7) << 4)));
        }
#pragma unroll
        for (int mi2 = 0; mi2 < 2; mi2++)
#pragma unroll
            for (int ni = 0; ni < 4; ni++)
                oa[mi2][ni] = __builtin_amdgcn_mfma_f32_16x16x32_f16(va[mi2], pb[ni], oa[mi2][ni], 0, 0, 0);
    }

#pragma unroll
    for (int mi2 = 0; mi2 < 2; mi2++)
#pragma unroll
        for (int ni = 0; ni < 4; ni++) {
            f16 t4[4];
#pragma unroll
            for (int j = 0; j < 4; j++) t4[j] = (f16)(oa[mi2][ni][j] * inv[ni]);
            int qq = ni * 16 + lr;
            *(uint2*)(sm + 12288 + qq * 64 + ((mi2 * 32 + kq * 8) ^ ((qq & 3) << 4))) =
                *(const uint2*)t4;
        }
    __syncthreads();

    f16* dst = aw + ((size_t)(wl * 64 + lane)) * CC + h * 32;
#pragma unroll
    for (int c = 0; c < 4; c++) {
        uint4 wv = *(const uint4*)(sm + 12288 + lane * 64 +
                                   ((c * 16) ^ ((lane & 3) << 4)));
        *(uint4*)(dst + c * 8) = wv;
    }
}

extern "C" void kernel_launch(void* const* d_in, const int* in_sizes, int n_in,
                              void* d_out, int out_size, void* d_ws, size_t ws_size,
                              hipStream_t stream) {
    (void)in_sizes; (void)n_in; (void)out_size; (void)ws_size;
    const float* x      = (const float*)d_in[0];
    const float* g1     = (const float*)d_in[1];
    const float* b1     = (const float*)d_in[2];
    const float* qkv_w  = (const float*)d_in[3];
    const float* qkv_b  = (const float*)d_in[4];
    const float* rpb    = (const float*)d_in[5];
    const float* proj_w = (const float*)d_in[6];
    const float* proj_b = (const float*)d_in[7];
    const float* g2     = (const float*)d_in[8];
    const float* b2     = (const float*)d_in[9];
    const float* fc1_w  = (const float*)d_in[10];
    const float* fc1_b  = (const float*)d_in[11];
    const float* fc2_w  = (const float*)d_in[12];
    const float* fc2_b  = (const float*)d_in[13];
    float* out = (float*)d_out;
    char* ws = (char*)d_ws;
    f16* wq = (f16*)(ws + OFF_WQ);
    f16* wp = (f16*)(ws + OFF_WP);
    f16* w1 = (f16*)(ws + OFF_W1);
    f16* w2 = (f16*)(ws + OFF_W2);
    f16* awb = (f16*)(ws + OFF_R1);
    static constexpr size_t QSZ = (size_t)CWINS * 8 * 64 * 32 * 2; // 16,777,216 B
    f16* hwin = (f16*)(ws + OFF_R2);
    f16* qb   = (f16*)(ws + OFF_R2 + QSZ);
    f16* kb   = (f16*)(ws + OFF_R2 + 2 * QSZ);
    f16* vb   = (f16*)(ws + OFF_R2 + 3 * QSZ);
    f16* m_in = (f16*)(ws + OFF_R2);

    k_cvt<<<768, 256, 0, stream>>>(qkv_w, wq, 768 * 256);
    k_cvt<<<256, 256, 0, stream>>>(proj_w, wp, 256 * 256);
    k_cvt<<<1024, 256, 0, stream>>>(fc1_w, w1, 1024 * 256);
    k_cvt<<<1024, 256, 0, stream>>>(fc2_w, w2, 1024 * 256);

    // --- attention phase: per chunk LN1 -> QKV -> attn (writes full AW) ---
    for (int c = 0; c < ACH; c++) {
        k_ln<<<AROWS / 4, 256, 0, stream>>>(x, g1, b1, hwin, c * AROWS);
        k_qkv<<<dim3(AROWS / 128, 6), 256, 0, stream>>>(
            hwin, wq, qkv_b, qb, kb, vb);
        k_attn<<<CWINS * 8, 64, 0, stream>>>(
            qb, kb, vb, rpb, awb + (size_t)c * AROWS * CC, c * CWINS);
    }
    // proj over full M, fused un-shift + residual -> out, fused LN2 -> m_in
    k_proj<<<ROWS / 64, 256, 0, stream>>>(awb, wp, proj_b, x, out, m_in, g2, b2);

    // --- fused MLP (no mh round-trip), single launch over full M ---
    k_mlp2<<<ROWS / 64, 256, 0, stream>>>(m_in, w1, w2, fc1_b, fc2_b, out);
}

// Round 12
// 703.857 us; speedup vs baseline: 1.0446x; 1.0446x over previous
//
#include <hip/hip_runtime.h>
#include <hip/hip_bf16.h>
#include <stdint.h>

using f16 = _Float16;
typedef _Float16 f16x8 __attribute__((ext_vector_type(8)));
typedef float f32x4 __attribute__((ext_vector_type(4)));

static constexpr int HW = 4096;        // H*W
static constexpr int CC = 256;         // channels
static constexpr int ROWS = 131072;    // B*H*W
static constexpr int ACH = 4;          // attention-phase chunks
static constexpr int AROWS = ROWS / ACH;      // 32768 rows / chunk
static constexpr int CWINS = AROWS / 64;      // 512 windows / chunk
static constexpr int SSH = 4;          // shift

// workspace layout (bytes)
static constexpr size_t OFF_WQ = 0;                               // qkv_w f16  768*256
static constexpr size_t OFF_WP = OFF_WQ + (size_t)768*256*2;      // proj_w f16 256*256
static constexpr size_t OFF_W1 = OFF_WP + (size_t)256*256*2;      // fc1_w f16  1024*256
static constexpr size_t OFF_W2 = OFF_W1 + (size_t)1024*256*2;     // fc2_w f16  256*1024
static constexpr size_t OFF_R1 = OFF_W2 + (size_t)256*1024*2;     // 67,108,864 B region
static constexpr size_t OFF_R2 = OFF_R1 + (size_t)ROWS*CC*2;      // 67,108,864 B region
// R1: AW full (131072x256 f16). R2: hwin chunk + Q + K + V -> then m_in full.

__device__ __forceinline__ void gload16(void* lds, const void* g) {
    __builtin_amdgcn_global_load_lds(
        (const __attribute__((address_space(1))) unsigned int*)g,
        (__attribute__((address_space(3))) unsigned int*)lds, 16, 0, 0);
}

__global__ void k_cvt(const float* __restrict__ s, f16* __restrict__ d, int n) {
    int i = blockIdx.x * 256 + threadIdx.x;
    if (i < n) d[i] = (f16)s[i];
}

// LayerNorm over C=256, dest row (windowed+rolled) gathers from source row of x.
__global__ __launch_bounds__(256) void k_ln(const float* __restrict__ x,
                                            const float* __restrict__ g,
                                            const float* __restrict__ be,
                                            f16* __restrict__ dst, int rowbase) {
    int lrow = blockIdx.x * 4 + (threadIdx.x >> 6);
    int grow = rowbase + lrow;
    int lane = threadIdx.x & 63;
    int n = grow & 63, win = (grow >> 6) & 63, b = grow >> 12;
    int hh  = ((win >> 3) << 3) | (n >> 3);
    int wwc = ((win & 7) << 3) | (n & 7);
    int ho = (hh + SSH) & 63, wo = (wwc + SSH) & 63;
    size_t srow = (size_t)b * HW + ho * 64 + wo;
    float4 v = ((const float4*)(x + srow * CC))[lane];
    float s  = v.x + v.y + v.z + v.w;
    float s2 = v.x*v.x + v.y*v.y + v.z*v.z + v.w*v.w;
#pragma unroll
    for (int off = 32; off; off >>= 1) { s += __shfl_xor(s, off); s2 += __shfl_xor(s2, off); }
    float mean = s * (1.f/256.f);
    float rstd = rsqrtf(s2 * (1.f/256.f) - mean*mean + 1e-5f);
    float4 gv = ((const float4*)g)[lane];
    float4 bv = ((const float4*)be)[lane];
    f16 ob[4];
    ob[0] = (f16)((v.x-mean)*rstd*gv.x + bv.x);
    ob[1] = (f16)((v.y-mean)*rstd*gv.y + bv.y);
    ob[2] = (f16)((v.z-mean)*rstd*gv.z + bv.z);
    ob[3] = (f16)((v.w-mean)*rstd*gv.w + bv.w);
    *(uint2*)(dst + (size_t)lrow * CC + lane * 4) = *(const uint2*)ob;
}

// QKV GEMM: out = A * Wt^T (+bias), 128x128 tile, BK=32, 2-phase double-buffer.
__global__ __launch_bounds__(256) void k_qkv(const f16* __restrict__ A,
                                             const f16* __restrict__ Wt,
                                             const float* __restrict__ bias,
                                             f16* __restrict__ q, f16* __restrict__ kk,
                                             f16* __restrict__ vv) {
    __shared__ f16 As[2][128 * 32];
    __shared__ f16 Bs[2][128 * 32];
    const int tid = threadIdx.x;
    const int m0 = blockIdx.x * 128, n0 = blockIdx.y * 128;
    const int wave = tid >> 6, lane = tid & 63;
    const int wm = (wave >> 1) * 64, wn = (wave & 1) * 64;
    const int lr = lane & 15, kq = lane >> 4;
    const int i0 = wave * 128 + lane;
    const int r0 = i0 >> 2, c0 = (i0 & 3) * 8;
    const int i1 = i0 + 64;
    const int r1 = i1 >> 2, c1 = (i1 & 3) * 8;
    const int base0 = wave * 1024, base1 = base0 + 512;

    auto stage = [&](int b, int k0) {
        gload16(&As[b][base0], &A [(size_t)(m0 + r0) * CC + k0 + c0]);
        gload16(&Bs[b][base0], &Wt[(size_t)(n0 + r0) * CC + k0 + c0]);
        gload16(&As[b][base1], &A [(size_t)(m0 + r1) * CC + k0 + c1]);
        gload16(&Bs[b][base1], &Wt[(size_t)(n0 + r1) * CC + k0 + c1]);
    };

    f32x4 acc[4][4];
#pragma unroll
    for (int i = 0; i < 4; i++)
#pragma unroll
        for (int j = 0; j < 4; j++) acc[i][j] = f32x4{0.f, 0.f, 0.f, 0.f};

    stage(0, 0);
    __syncthreads();
    for (int s = 0; s < 8; s++) {
        int cur = s & 1;
        if (s + 1 < 8) stage(cur ^ 1, (s + 1) * 32);
        f16x8 af[4], bfv[4];
#pragma unroll
        for (int i = 0; i < 4; i++) {
            af[i]  = *(const f16x8*)(&As[cur][(wm + i * 16 + lr) * 32 + kq * 8]);
            bfv[i] = *(const f16x8*)(&Bs[cur][(wn + i * 16 + lr) * 32 + kq * 8]);
        }
#pragma unroll
        for (int mi = 0; mi < 4; mi++)
#pragma unroll
            for (int ni = 0; ni < 4; ni++)
                acc[mi][ni] = __builtin_amdgcn_mfma_f32_16x16x32_f16(af[mi], bfv[ni], acc[mi][ni], 0, 0, 0);
        __syncthreads();
    }

#pragma unroll
    for (int mi = 0; mi < 4; mi++)
#pragma unroll
        for (int ni = 0; ni < 4; ni++)
#pragma unroll
            for (int j = 0; j < 4; j++) {
                int lrow = m0 + wm + mi * 16 + kq * 4 + j;   // C/D: row=(lane>>4)*4+j
                int gcol = n0 + wn + ni * 16 + lr;           //      col=lane&15
                float val = acc[mi][ni][j] + bias[gcol];
                int s = gcol >> 8, h2 = (gcol >> 5) & 7, d = gcol & 31;
                if (s == 0) val *= 0.1767766952966369f;  // HD^-0.5
                f16* dst = (s == 0) ? q : (s == 1 ? kk : vv);
                int winl = lrow >> 6, n = lrow & 63;
                dst[(((size_t)winl * 8 + h2) * 64 + n) * 32 + d] = (f16)val;
            }
}

// proj GEMM, tile 64 rows x 256 cols (full row per block), 4 waves (1x4 of 64x64).
// Epilogue: + proj bias, + un-shift scatter + shortcut residual -> d_out (f32),
// then in-block LayerNorm2 over the complete 256-wide row -> m_in (f16).
__global__ __launch_bounds__(256, 2) void k_proj(const f16* __restrict__ A,
                                                 const f16* __restrict__ Wt,
                                                 const float* __restrict__ bias,
                                                 const float* __restrict__ x_in,
                                                 float* __restrict__ outf,
                                                 f16* __restrict__ m_out,
                                                 const float* __restrict__ g2,
                                                 const float* __restrict__ b2) {
    __shared__ f16 As[2][64 * 32];
    __shared__ f16 Bs[2][256 * 32];
    __shared__ float rsum[4][64];
    __shared__ float rsq[4][64];
    const int tid = threadIdx.x;
    const int m0 = blockIdx.x * 64;
    const int wave = tid >> 6, lane = tid & 63;
    const int lr = lane & 15, kq = lane >> 4;
    const int ar = tid >> 2, ac = (tid & 3) * 8;   // A stage: 256 chunks, 1/thread

    auto stage = [&](int b, int k0) {
        gload16(&As[b][wave * 512], &A[(size_t)(m0 + ar) * CC + k0 + ac]);
#pragma unroll
        for (int r = 0; r < 4; r++)
            gload16(&Bs[b][(r * 256 + wave * 64) * 8],
                    &Wt[(size_t)(r * 64 + ar) * CC + k0 + ac]);
    };

    f32x4 acc[4][4];
#pragma unroll
    for (int i = 0; i < 4; i++)
#pragma unroll
        for (int j = 0; j < 4; j++) acc[i][j] = f32x4{0.f, 0.f, 0.f, 0.f};

    stage(0, 0);
    __syncthreads();
    for (int s = 0; s < 8; s++) {
        int cur = s & 1;
        if (s + 1 < 8) stage(cur ^ 1, (s + 1) * 32);
        f16x8 af[4], bfv[4];
#pragma unroll
        for (int i = 0; i < 4; i++) {
            af[i]  = *(const f16x8*)(&As[cur][(i * 16 + lr) * 32 + kq * 8]);
            bfv[i] = *(const f16x8*)(&Bs[cur][(wave * 64 + i * 16 + lr) * 32 + kq * 8]);
        }
#pragma unroll
        for (int mi = 0; mi < 4; mi++)
#pragma unroll
            for (int ni = 0; ni < 4; ni++)
                acc[mi][ni] = __builtin_amdgcn_mfma_f32_16x16x32_f16(af[mi], bfv[ni], acc[mi][ni], 0, 0, 0);
        __syncthreads();
    }

    // ---- epilogue: x2 = proj + bias + shortcut (per un-shift scatter) ----
    int srows[4][4];
#pragma unroll
    for (int mi = 0; mi < 4; mi++)
#pragma unroll
        for (int j = 0; j < 4; j++) {
            int row = m0 + mi * 16 + kq * 4 + j;       // windowed-order global row
            int n = row & 63, win = (row >> 6) & 63, b = row >> 12;
            int hh  = ((win >> 3) << 3) | (n >> 3);
            int wwc = ((win & 7) << 3) | (n & 7);
            int ho = (hh + SSH) & 63, wo = (wwc + SSH) & 63;
            srows[mi][j] = b * HW + ho * 64 + wo;
        }
    float bv[4], gv[4], b2v[4];
#pragma unroll
    for (int ni = 0; ni < 4; ni++) {
        int gcol = wave * 64 + ni * 16 + lr;
        bv[ni] = bias[gcol]; gv[ni] = g2[gcol]; b2v[ni] = b2[gcol];
    }
    float ps[4][4], qs[4][4];
#pragma unroll
    for (int mi = 0; mi < 4; mi++)
#pragma unroll
        for (int j = 0; j < 4; j++) { ps[mi][j] = 0.f; qs[mi][j] = 0.f; }
#pragma unroll
    for (int mi = 0; mi < 4; mi++)
#pragma unroll
        for (int ni = 0; ni < 4; ni++) {
            int gcol = wave * 64 + ni * 16 + lr;
#pragma unroll
            for (int j = 0; j < 4; j++) {
                size_t idx = (size_t)srows[mi][j] * CC + gcol;
                float v = acc[mi][ni][j] + bv[ni] + x_in[idx];
                acc[mi][ni][j] = v;
                outf[idx] = v;
                ps[mi][j] += v; qs[mi][j] += v * v;
            }
        }
#pragma unroll
    for (int off = 1; off < 16; off <<= 1)
#pragma unroll
        for (int mi = 0; mi < 4; mi++)
#pragma unroll
            for (int j = 0; j < 4; j++) {
                ps[mi][j] += __shfl_xor(ps[mi][j], off);
                qs[mi][j] += __shfl_xor(qs[mi][j], off);
            }
    if (lr == 0) {
#pragma unroll
        for (int mi = 0; mi < 4; mi++)
#pragma unroll
            for (int j = 0; j < 4; j++) {
                int rl = mi * 16 + kq * 4 + j;
                rsum[wave][rl] = ps[mi][j];
                rsq[wave][rl]  = qs[mi][j];
            }
    }
    __syncthreads();
    float mean_a[4][4], rstd_a[4][4];
#pragma unroll
    for (int mi = 0; mi < 4; mi++)
#pragma unroll
        for (int j = 0; j < 4; j++) {
            int rl = mi * 16 + kq * 4 + j;
            float s  = rsum[0][rl] + rsum[1][rl] + rsum[2][rl] + rsum[3][rl];
            float s2 = rsq[0][rl] + rsq[1][rl] + rsq[2][rl] + rsq[3][rl];
            float mean = s * (1.f/256.f);
            float var  = s2 * (1.f/256.f) - mean * mean;
            mean_a[mi][j] = mean;
            rstd_a[mi][j] = rsqrtf(var + 1e-5f);
        }
#pragma unroll
    for (int mi = 0; mi < 4; mi++)
#pragma unroll
        for (int ni = 0; ni < 4; ni++) {
            int gcol = wave * 64 + ni * 16 + lr;
#pragma unroll
            for (int j = 0; j < 4; j++) {
                float m = (acc[mi][ni][j] - mean_a[mi][j]) * rstd_a[mi][j] * gv[ni] + b2v[ni];
                m_out[(size_t)srows[mi][j] * CC + gcol] = (f16)m;
            }
        }
}

// Fused MLP: out += fc2(gelu(fc1(m_in))); NO mh round-trip.
// fc1 operand-SWAPPED (A := w1, B := x) so the j-dim walks consecutive hid ->
// gelu'd h written as aligned uint2 into swizzled h[q][hid].
// CHEAP GELU (R11-validated): v * rcp(1 + exp(-1.5957691*v - 0.0713548*v^3))
// replaces the precise-division tanh chain (~halves gelu VALU ops).
// fc2: h swizzled b128 reads, acc2 persistent across nb (K-loop accumulator).
__global__ __launch_bounds__(256) void k_mlp2(const f16* __restrict__ A,
                                              const f16* __restrict__ w1,
                                              const f16* __restrict__ w2,
                                              const float* __restrict__ fb1,
                                              const float* __restrict__ fb2,
                                              float* __restrict__ out) {
    __shared__ char sm[49152];
    char* hbuf = sm;                 // [64][128] f16, row stride 256B, XOR-swizzled
    char* S    = sm + 16384;         // 32KB: fc1 staging (As 8K + Bs1 16K) / fc2 Bs2 32K
    f16* As  = (f16*)S;              // [2][64*32]
    f16* Bs1 = (f16*)(S + 8192);     // [2][128*32]
    f16* Bs2 = (f16*)S;              // [2][256*32]
    const int tid = threadIdx.x, wave = tid >> 6, lane = tid & 63;
    const int lr = lane & 15, kq = lane >> 4;
    const int m0 = blockIdx.x * 64;
    const int ar = tid >> 2, ac = (tid & 3) * 8;

    f32x4 acc2[4][4];
#pragma unroll
    for (int i = 0; i < 4; i++)
#pragma unroll
        for (int j = 0; j < 4; j++) acc2[i][j] = f32x4{0.f, 0.f, 0.f, 0.f};

    for (int nb = 0; nb < 8; nb++) {
        auto stage1 = [&](int b, int k0) {
            gload16(&As[b * 2048 + wave * 512], &A[(size_t)(m0 + ar) * CC + k0 + ac]);
            gload16(&Bs1[b * 4096 + wave * 512],
                    &w1[(size_t)(nb * 128 + ar) * CC + k0 + ac]);
            gload16(&Bs1[b * 4096 + 2048 + wave * 512],
                    &w1[(size_t)(nb * 128 + 64 + ar) * CC + k0 + ac]);
        };
        // ---- fc1 slice (swapped): acc1[hid frags][q frags] ----
        f32x4 acc1[2][4];
#pragma unroll
        for (int i = 0; i < 2; i++)
#pragma unroll
            for (int j = 0; j < 4; j++) acc1[i][j] = f32x4{0.f, 0.f, 0.f, 0.f};
        stage1(0, 0);
        __syncthreads();
#pragma unroll
        for (int ks = 0; ks < 8; ks++) {
            int cur = ks & 1;
            if (ks + 1 < 8) stage1(cur ^ 1, (ks + 1) * 32);
            f16x8 aw1[2], bx[4];
#pragma unroll
            for (int hi = 0; hi < 2; hi++)
                aw1[hi] = *(const f16x8*)(&Bs1[cur * 4096 +
                                               (wave * 32 + hi * 16 + lr) * 32 + kq * 8]);
#pragma unroll
            for (int qi = 0; qi < 4; qi++)
                bx[qi] = *(const f16x8*)(&As[cur * 2048 + (qi * 16 + lr) * 32 + kq * 8]);
#pragma unroll
            for (int hi = 0; hi < 2; hi++)
#pragma unroll
                for (int qi = 0; qi < 4; qi++)
                    acc1[hi][qi] = __builtin_amdgcn_mfma_f32_16x16x32_f16(
                        aw1[hi], bx[qi], acc1[hi][qi], 0, 0, 0);
            __syncthreads();
        }
        // ---- cheap gelu -> h (vectorized uint2, swizzled), stage fc2 B after ----
#pragma unroll
        for (int hi = 0; hi < 2; hi++) {
            float4 bb4 = *(const float4*)&fb1[nb * 128 + wave * 32 + hi * 16 + kq * 4];
            const float bb[4] = {bb4.x, bb4.y, bb4.z, bb4.w};
            const int hidb = wave * 64 + hi * 32 + kq * 8;   // byte = 2*hid base
#pragma unroll
            for (int qi = 0; qi < 4; qi++) {
                f16 t4[4];
#pragma unroll
                for (int j = 0; j < 4; j++) {
                    float v = acc1[hi][qi][j] + bb[j];
                    // gelu(v) = v * sigmoid(1.5957691*v + 0.0713548*v^3)
                    float e = __expf(v * (-1.5957691216f - 0.07135482f * v * v));
                    t4[j] = (f16)(v * __builtin_amdgcn_rcpf(1.f + e));
                }
                int qrow = qi * 16 + lr;
                *(uint2*)(hbuf + qrow * 256 + (hidb ^ ((qrow & 7) << 4))) =
                    *(const uint2*)t4;
            }
        }
        auto stage2 = [&](int b, int k0) {
#pragma unroll
            for (int t = 0; t < 4; t++)
                gload16(&Bs2[b * 8192 + t * 2048 + wave * 512],
                        &w2[(size_t)(t * 64 + ar) * 1024 + nb * 128 + k0 + ac]);
        };
        stage2(0, 0);
        __syncthreads();     // h visible + Bs2[0] landed (barrier drains vmcnt)
        // ---- fc2 partial: acc2[64 q rows][wave's 64 out cols] += h @ w2_nb^T ----
#pragma unroll
        for (int ks = 0; ks < 4; ks++) {
            int cur = ks & 1;
            if (ks + 1 < 4) stage2(cur ^ 1, (ks + 1) * 32);
            f16x8 ah[4], bw[4];
#pragma unroll
            for (int mi = 0; mi < 4; mi++) {
                int row = mi * 16 + lr;
                ah[mi] = *(const f16x8*)(hbuf + row * 256 +
                                         ((ks * 64 + kq * 16) ^ ((row & 7) << 4)));
            }
#pragma unroll
            for (int ni = 0; ni < 4; ni++)
                bw[ni] = *(const f16x8*)(&Bs2[cur * 8192 +
                                              (wave * 64 + ni * 16 + lr) * 32 + kq * 8]);
#pragma unroll
            for (int mi = 0; mi < 4; mi++)
#pragma unroll
                for (int ni = 0; ni < 4; ni++)
                    acc2[mi][ni] = __builtin_amdgcn_mfma_f32_16x16x32_f16(
                        ah[mi], bw[ni], acc2[mi][ni], 0, 0, 0);
            __syncthreads();
        }
    }

    // ---- epilogue: out += acc2 + fb2 (coalesced 64B f32 segments) ----
#pragma unroll
    for (int mi = 0; mi < 4; mi++)
#pragma unroll
        for (int ni = 0; ni < 4; ni++)
#pragma unroll
            for (int j = 0; j < 4; j++) {
                int qrow = m0 + mi * 16 + kq * 4 + j;
                int oc = wave * 64 + ni * 16 + lr;
                size_t idx = (size_t)qrow * CC + oc;
                out[idx] = out[idx] + acc2[mi][ni][j] + fb2[oc];
            }
}

// MFMA attention: one wave per (window, head). S^T = mfma(K,Q); in-register
// softmax over keys; j-packed b64 swizzled LDS P-transpose; O^T = mfma(V^T, P);
// swizzled O-transpose -> 4 coalesced stores. 17.3KB LDS.
__global__ __launch_bounds__(64) void k_attn(const f16* __restrict__ q,
                                             const f16* __restrict__ kk,
                                             const f16* __restrict__ vv,
                                             const float* __restrict__ rpb,
                                             f16* __restrict__ aw, int winbase) {
    __shared__ char sm[17408];      // P[64][64] 8KB | VT[32][64] 4KB | O[64][32] 4KB | rl 900B
    float* rl = (float*)(sm + 16384);
    const int wl = blockIdx.x >> 3, h = blockIdx.x & 7;
    const int lane = threadIdx.x;
    const int lr = lane & 15, kq = lane >> 4;
    const size_t base = ((size_t)wl * 8 + h) * 2048;

    for (int i = lane; i < 225; i += 64) rl[i] = rpb[i * 8 + h];

    {
        f16 vr[32];
        const uint4* vs = (const uint4*)(vv + base + lane * 32);
#pragma unroll
        for (int c = 0; c < 4; c++) *(uint4*)&vr[c * 8] = vs[c];
#pragma unroll
        for (int d = 0; d < 32; d++)
            *(f16*)(sm + 8192 + d * 128 + ((lane * 2) ^ ((d & 7) << 4))) = vr[d];
    }

    f16x8 kf[4], qf[4];
#pragma unroll
    for (int t = 0; t < 4; t++) {
        kf[t] = *(const f16x8*)(kk + base + (size_t)(t * 16 + lr) * 32 + kq * 8);
        qf[t] = *(const f16x8*)(q  + base + (size_t)(t * 16 + lr) * 32 + kq * 8);
    }

    f32x4 st[4][4];
#pragma unroll
    for (int mi = 0; mi < 4; mi++)
#pragma unroll
        for (int ni = 0; ni < 4; ni++) st[mi][ni] = f32x4{0.f, 0.f, 0.f, 0.f};
#pragma unroll
    for (int mi = 0; mi < 4; mi++)
#pragma unroll
        for (int ni = 0; ni < 4; ni++)
            st[mi][ni] = __builtin_amdgcn_mfma_f32_16x16x32_f16(kf[mi], qf[ni], st[mi][ni], 0, 0, 0);

    __syncthreads();

    const int gwin = (winbase + wl) & 63;
    const int wh = gwin >> 3, ww = gwin & 7;
    int yq[4], xq[4], rq[4];
#pragma unroll
    for (int ni = 0; ni < 4; ni++) {
        int qq = ni * 16 + lr;
        yq[ni] = qq >> 3; xq[ni] = qq & 7;
        rq[ni] = ((wh < 7) ? 0 : ((yq[ni] < 4) ? 1 : 2)) * 3 +
                 ((ww < 7) ? 0 : ((xq[ni] < 4) ? 1 : 2));
    }
#pragma unroll
    for (int mi = 0; mi < 4; mi++)
#pragma unroll
        for (int j = 0; j < 4; j++) {
            int kt = mi * 16 + kq * 4 + j;
            int yk = kt >> 3, xk = kt & 7;
            int rk = ((wh < 7) ? 0 : ((yk < 4) ? 1 : 2)) * 3 +
                     ((ww < 7) ? 0 : ((xk < 4) ? 1 : 2));
#pragma unroll
            for (int ni = 0; ni < 4; ni++) {
                float b = rl[(yq[ni] - yk + 7) * 15 + (xq[ni] - xk + 7)];
                if (rq[ni] != rk) b -= 100.f;
                st[mi][ni][j] += b;
            }
        }

    float mx[4] = {-1e30f, -1e30f, -1e30f, -1e30f};
#pragma unroll
    for (int mi = 0; mi < 4; mi++)
#pragma unroll
        for (int ni = 0; ni < 4; ni++)
#pragma unroll
            for (int j = 0; j < 4; j++) mx[ni] = fmaxf(mx[ni], st[mi][ni][j]);
#pragma unroll
    for (int ni = 0; ni < 4; ni++) {
        mx[ni] = fmaxf(mx[ni], __shfl_xor(mx[ni], 16));
        mx[ni] = fmaxf(mx[ni], __shfl_xor(mx[ni], 32));
    }
    float sme[4] = {0.f, 0.f, 0.f, 0.f};
#pragma unroll
    for (int mi = 0; mi < 4; mi++)
#pragma unroll
        for (int ni = 0; ni < 4; ni++)
#pragma unroll
            for (int j = 0; j < 4; j++) {
                float e = __expf(st[mi][ni][j] - mx[ni]);
                st[mi][ni][j] = e;
                sme[ni] += e;
            }
#pragma unroll
    for (int ni = 0; ni < 4; ni++) {
        sme[ni] += __shfl_xor(sme[ni], 16);
        sme[ni] += __shfl_xor(sme[ni], 32);
    }
    float inv[4];
#pragma unroll
    for (int ni = 0; ni < 4; ni++) inv[ni] = 1.f / sme[ni];

#pragma unroll
    for (int mi = 0; mi < 4; mi++)
#pragma unroll
        for (int ni = 0; ni < 4; ni++) {
            f16 t4[4];
#pragma unroll
            for (int j = 0; j < 4; j++) t4[j] = (f16)st[mi][ni][j];
            int qq = ni * 16 + lr;
            *(uint2*)(sm + qq * 128 + ((mi * 32 + kq * 8) ^ ((qq & 7) << 4))) =
                *(const uint2*)t4;
        }
    __syncthreads();

    f32x4 oa[2][4];
#pragma unroll
    for (int mi2 = 0; mi2 < 2; mi2++)
#pragma unroll
        for (int ni = 0; ni < 4; ni++) oa[mi2][ni] = f32x4{0.f, 0.f, 0.f, 0.f};
#pragma unroll
    for (int ks = 0; ks < 2; ks++) {
        f16x8 va[2], pb[4];
#pragma unroll
        for (int mi2 = 0; mi2 < 2; mi2++) {
            int row = mi2 * 16 + lr;
            va[mi2] = *(const f16x8*)(sm + 8192 + row * 128 +
                                      ((ks * 64 + kq * 16) ^ ((row & 7) << 4)));
        }
#pragma unroll
        for (int ni = 0; ni < 4; ni++) {
            int qq = ni * 16 + lr;
            pb[ni] = *(const f16x8*)(sm + qq * 128 +
                                     ((ks * 64 + kq * 16) ^ ((qq & 7) << 4)));
        }
#pragma unroll
        for (int mi2 = 0; mi2 < 2; mi2++)
#pragma unroll
            for (int ni = 0; ni < 4; ni++)
                oa[mi2][ni] = __builtin_amdgcn_mfma_f32_16x16x32_f16(va[mi2], pb[ni], oa[mi2][ni], 0, 0, 0);
    }

#pragma unroll
    for (int mi2 = 0; mi2 < 2; mi2++)
#pragma unroll
        for (int ni = 0; ni < 4; ni++) {
            f16 t4[4];
#pragma unroll
            for (int j = 0; j < 4; j++) t4[j] = (f16)(oa[mi2][ni][j] * inv[ni]);
            int qq = ni * 16 + lr;
            *(uint2*)(sm + 12288 + qq * 64 + ((mi2 * 32 + kq * 8) ^ ((qq & 3) << 4))) =
                *(const uint2*)t4;
        }
    __syncthreads();

    f16* dst = aw + ((size_t)(wl * 64 + lane)) * CC + h * 32;
#pragma unroll
    for (int c = 0; c < 4; c++) {
        uint4 wv = *(const uint4*)(sm + 12288 + lane * 64 +
                                   ((c * 16) ^ ((lane & 3) << 4)));
        *(uint4*)(dst + c * 8) = wv;
    }
}

extern "C" void kernel_launch(void* const* d_in, const int* in_sizes, int n_in,
                              void* d_out, int out_size, void* d_ws, size_t ws_size,
                              hipStream_t stream) {
    (void)in_sizes; (void)n_in; (void)out_size; (void)ws_size;
    const float* x      = (const float*)d_in[0];
    const float* g1     = (const float*)d_in[1];
    const float* b1     = (const float*)d_in[2];
    const float* qkv_w  = (const float*)d_in[3];
    const float* qkv_b  = (const float*)d_in[4];
    const float* rpb    = (const float*)d_in[5];
    const float* proj_w = (const float*)d_in[6];
    const float* proj_b = (const float*)d_in[7];
    const float* g2     = (const float*)d_in[8];
    const float* b2     = (const float*)d_in[9];
    const float* fc1_w  = (const float*)d_in[10];
    const float* fc1_b  = (const float*)d_in[11];
    const float* fc2_w  = (const float*)d_in[12];
    const float* fc2_b  = (const float*)d_in[13];
    float* out = (float*)d_out;
    char* ws = (char*)d_ws;
    f16* wq = (f16*)(ws + OFF_WQ);
    f16* wp = (f16*)(ws + OFF_WP);
    f16* w1 = (f16*)(ws + OFF_W1);
    f16* w2 = (f16*)(ws + OFF_W2);
    f16* awb = (f16*)(ws + OFF_R1);
    static constexpr size_t QSZ = (size_t)CWINS * 8 * 64 * 32 * 2; // 16,777,216 B
    f16* hwin = (f16*)(ws + OFF_R2);
    f16* qb   = (f16*)(ws + OFF_R2 + QSZ);
    f16* kb   = (f16*)(ws + OFF_R2 + 2 * QSZ);
    f16* vb   = (f16*)(ws + OFF_R2 + 3 * QSZ);
    f16* m_in = (f16*)(ws + OFF_R2);

    k_cvt<<<768, 256, 0, stream>>>(qkv_w, wq, 768 * 256);
    k_cvt<<<256, 256, 0, stream>>>(proj_w, wp, 256 * 256);
    k_cvt<<<1024, 256, 0, stream>>>(fc1_w, w1, 1024 * 256);
    k_cvt<<<1024, 256, 0, stream>>>(fc2_w, w2, 1024 * 256);

    // --- attention phase: per chunk LN1 -> QKV -> attn (writes full AW) ---
    for (int c = 0; c < ACH; c++) {
        k_ln<<<AROWS / 4, 256, 0, stream>>>(x, g1, b1, hwin, c * AROWS);
        k_qkv<<<dim3(AROWS / 128, 6), 256, 0, stream>>>(
            hwin, wq, qkv_b, qb, kb, vb);
        k_attn<<<CWINS * 8, 64, 0, stream>>>(
            qb, kb, vb, rpb, awb + (size_t)c * AROWS * CC, c * CWINS);
    }
    // proj over full M, fused un-shift + residual -> out, fused LN2 -> m_in
    k_proj<<<ROWS / 64, 256, 0, stream>>>(awb, wp, proj_b, x, out, m_in, g2, b2);

    // --- fused MLP (no mh round-trip), single launch over full M ---
    k_mlp2<<<ROWS / 64, 256, 0, stream>>>(m_in, w1, w2, fc1_b, fc2_b, out);
}

// Round 13
// 703.239 us; speedup vs baseline: 1.0456x; 1.0009x over previous
//
#include <hip/hip_runtime.h>
#include <hip/hip_bf16.h>
#include <stdint.h>

using f16 = _Float16;
typedef _Float16 f16x8 __attribute__((ext_vector_type(8)));
typedef float f32x4 __attribute__((ext_vector_type(4)));

static constexpr int HW = 4096;        // H*W
static constexpr int CC = 256;         // channels
static constexpr int ROWS = 131072;    // B*H*W
static constexpr int ACH = 4;          // attention-phase chunks
static constexpr int AROWS = ROWS / ACH;      // 32768 rows / chunk
static constexpr int CWINS = AROWS / 64;      // 512 windows / chunk
static constexpr int SSH = 4;          // shift

// workspace layout (bytes)
static constexpr size_t OFF_WQ = 0;                               // qkv_w f16  768*256
static constexpr size_t OFF_WP = OFF_WQ + (size_t)768*256*2;      // proj_w f16 256*256
static constexpr size_t OFF_W1 = OFF_WP + (size_t)256*256*2;      // fc1_w f16  1024*256
static constexpr size_t OFF_W2 = OFF_W1 + (size_t)1024*256*2;     // fc2_w f16  256*1024
static constexpr size_t OFF_R1 = OFF_W2 + (size_t)256*1024*2;     // 67,108,864 B region
static constexpr size_t OFF_R2 = OFF_R1 + (size_t)ROWS*CC*2;      // 67,108,864 B region
// R1: AW full (131072x256 f16). R2: hwin chunk + Q + K + V -> then m_in full.

__device__ __forceinline__ void gload16(void* lds, const void* g) {
    __builtin_amdgcn_global_load_lds(
        (const __attribute__((address_space(1))) unsigned int*)g,
        (__attribute__((address_space(3))) unsigned int*)lds, 16, 0, 0);
}

__global__ void k_cvt(const float* __restrict__ s, f16* __restrict__ d, int n) {
    int i = blockIdx.x * 256 + threadIdx.x;
    if (i < n) d[i] = (f16)s[i];
}

// LayerNorm over C=256, dest row (windowed+rolled) gathers from source row of x.
__global__ __launch_bounds__(256) void k_ln(const float* __restrict__ x,
                                            const float* __restrict__ g,
                                            const float* __restrict__ be,
                                            f16* __restrict__ dst, int rowbase) {
    int lrow = blockIdx.x * 4 + (threadIdx.x >> 6);
    int grow = rowbase + lrow;
    int lane = threadIdx.x & 63;
    int n = grow & 63, win = (grow >> 6) & 63, b = grow >> 12;
    int hh  = ((win >> 3) << 3) | (n >> 3);
    int wwc = ((win & 7) << 3) | (n & 7);
    int ho = (hh + SSH) & 63, wo = (wwc + SSH) & 63;
    size_t srow = (size_t)b * HW + ho * 64 + wo;
    float4 v = ((const float4*)(x + srow * CC))[lane];
    float s  = v.x + v.y + v.z + v.w;
    float s2 = v.x*v.x + v.y*v.y + v.z*v.z + v.w*v.w;
#pragma unroll
    for (int off = 32; off; off >>= 1) { s += __shfl_xor(s, off); s2 += __shfl_xor(s2, off); }
    float mean = s * (1.f/256.f);
    float rstd = rsqrtf(s2 * (1.f/256.f) - mean*mean + 1e-5f);
    float4 gv = ((const float4*)g)[lane];
    float4 bv = ((const float4*)be)[lane];
    f16 ob[4];
    ob[0] = (f16)((v.x-mean)*rstd*gv.x + bv.x);
    ob[1] = (f16)((v.y-mean)*rstd*gv.y + bv.y);
    ob[2] = (f16)((v.z-mean)*rstd*gv.z + bv.z);
    ob[3] = (f16)((v.w-mean)*rstd*gv.w + bv.w);
    *(uint2*)(dst + (size_t)lrow * CC + lane * 4) = *(const uint2*)ob;
}

// QKV GEMM: out = A * Wt^T (+bias), 128x128 tile, BK=32, 2-phase double-buffer.
__global__ __launch_bounds__(256) void k_qkv(const f16* __restrict__ A,
                                             const f16* __restrict__ Wt,
                                             const float* __restrict__ bias,
                                             f16* __restrict__ q, f16* __restrict__ kk,
                                             f16* __restrict__ vv) {
    __shared__ f16 As[2][128 * 32];
    __shared__ f16 Bs[2][128 * 32];
    const int tid = threadIdx.x;
    const int m0 = blockIdx.x * 128, n0 = blockIdx.y * 128;
    const int wave = tid >> 6, lane = tid & 63;
    const int wm = (wave >> 1) * 64, wn = (wave & 1) * 64;
    const int lr = lane & 15, kq = lane >> 4;
    const int i0 = wave * 128 + lane;
    const int r0 = i0 >> 2, c0 = (i0 & 3) * 8;
    const int i1 = i0 + 64;
    const int r1 = i1 >> 2, c1 = (i1 & 3) * 8;
    const int base0 = wave * 1024, base1 = base0 + 512;

    auto stage = [&](int b, int k0) {
        gload16(&As[b][base0], &A [(size_t)(m0 + r0) * CC + k0 + c0]);
        gload16(&Bs[b][base0], &Wt[(size_t)(n0 + r0) * CC + k0 + c0]);
        gload16(&As[b][base1], &A [(size_t)(m0 + r1) * CC + k0 + c1]);
        gload16(&Bs[b][base1], &Wt[(size_t)(n0 + r1) * CC + k0 + c1]);
    };

    f32x4 acc[4][4];
#pragma unroll
    for (int i = 0; i < 4; i++)
#pragma unroll
        for (int j = 0; j < 4; j++) acc[i][j] = f32x4{0.f, 0.f, 0.f, 0.f};

    stage(0, 0);
    __syncthreads();
    for (int s = 0; s < 8; s++) {
        int cur = s & 1;
        if (s + 1 < 8) stage(cur ^ 1, (s + 1) * 32);
        f16x8 af[4], bfv[4];
#pragma unroll
        for (int i = 0; i < 4; i++) {
            af[i]  = *(const f16x8*)(&As[cur][(wm + i * 16 + lr) * 32 + kq * 8]);
            bfv[i] = *(const f16x8*)(&Bs[cur][(wn + i * 16 + lr) * 32 + kq * 8]);
        }
#pragma unroll
        for (int mi = 0; mi < 4; mi++)
#pragma unroll
            for (int ni = 0; ni < 4; ni++)
                acc[mi][ni] = __builtin_amdgcn_mfma_f32_16x16x32_f16(af[mi], bfv[ni], acc[mi][ni], 0, 0, 0);
        __syncthreads();
    }

#pragma unroll
    for (int mi = 0; mi < 4; mi++)
#pragma unroll
        for (int ni = 0; ni < 4; ni++)
#pragma unroll
            for (int j = 0; j < 4; j++) {
                int lrow = m0 + wm + mi * 16 + kq * 4 + j;   // C/D: row=(lane>>4)*4+j
                int gcol = n0 + wn + ni * 16 + lr;           //      col=lane&15
                float val = acc[mi][ni][j] + bias[gcol];
                int s = gcol >> 8, h2 = (gcol >> 5) & 7, d = gcol & 31;
                if (s == 0) val *= 0.1767766952966369f;  // HD^-0.5
                f16* dst = (s == 0) ? q : (s == 1 ? kk : vv);
                int winl = lrow >> 6, n = lrow & 63;
                dst[(((size_t)winl * 8 + h2) * 64 + n) * 32 + d] = (f16)val;
            }
}

// proj GEMM, tile 64 rows x 256 cols (full row per block), 4 waves (1x4 of 64x64).
// Epilogue: + proj bias, + un-shift scatter + shortcut residual -> d_out (f32),
// then in-block LayerNorm2 over the complete 256-wide row -> m_in (f16).
__global__ __launch_bounds__(256, 2) void k_proj(const f16* __restrict__ A,
                                                 const f16* __restrict__ Wt,
                                                 const float* __restrict__ bias,
                                                 const float* __restrict__ x_in,
                                                 float* __restrict__ outf,
                                                 f16* __restrict__ m_out,
                                                 const float* __restrict__ g2,
                                                 const float* __restrict__ b2) {
    __shared__ f16 As[2][64 * 32];
    __shared__ f16 Bs[2][256 * 32];
    __shared__ float rsum[4][64];
    __shared__ float rsq[4][64];
    const int tid = threadIdx.x;
    const int m0 = blockIdx.x * 64;
    const int wave = tid >> 6, lane = tid & 63;
    const int lr = lane & 15, kq = lane >> 4;
    const int ar = tid >> 2, ac = (tid & 3) * 8;   // A stage: 256 chunks, 1/thread

    auto stage = [&](int b, int k0) {
        gload16(&As[b][wave * 512], &A[(size_t)(m0 + ar) * CC + k0 + ac]);
#pragma unroll
        for (int r = 0; r < 4; r++)
            gload16(&Bs[b][(r * 256 + wave * 64) * 8],
                    &Wt[(size_t)(r * 64 + ar) * CC + k0 + ac]);
    };

    f32x4 acc[4][4];
#pragma unroll
    for (int i = 0; i < 4; i++)
#pragma unroll
        for (int j = 0; j < 4; j++) acc[i][j] = f32x4{0.f, 0.f, 0.f, 0.f};

    stage(0, 0);
    __syncthreads();
    for (int s = 0; s < 8; s++) {
        int cur = s & 1;
        if (s + 1 < 8) stage(cur ^ 1, (s + 1) * 32);
        f16x8 af[4], bfv[4];
#pragma unroll
        for (int i = 0; i < 4; i++) {
            af[i]  = *(const f16x8*)(&As[cur][(i * 16 + lr) * 32 + kq * 8]);
            bfv[i] = *(const f16x8*)(&Bs[cur][(wave * 64 + i * 16 + lr) * 32 + kq * 8]);
        }
#pragma unroll
        for (int mi = 0; mi < 4; mi++)
#pragma unroll
            for (int ni = 0; ni < 4; ni++)
                acc[mi][ni] = __builtin_amdgcn_mfma_f32_16x16x32_f16(af[mi], bfv[ni], acc[mi][ni], 0, 0, 0);
        __syncthreads();
    }

    // ---- epilogue: x2 = proj + bias + shortcut (per un-shift scatter) ----
    int srows[4][4];
#pragma unroll
    for (int mi = 0; mi < 4; mi++)
#pragma unroll
        for (int j = 0; j < 4; j++) {
            int row = m0 + mi * 16 + kq * 4 + j;       // windowed-order global row
            int n = row & 63, win = (row >> 6) & 63, b = row >> 12;
            int hh  = ((win >> 3) << 3) | (n >> 3);
            int wwc = ((win & 7) << 3) | (n & 7);
            int ho = (hh + SSH) & 63, wo = (wwc + SSH) & 63;
            srows[mi][j] = b * HW + ho * 64 + wo;
        }
    float bv[4], gv[4], b2v[4];
#pragma unroll
    for (int ni = 0; ni < 4; ni++) {
        int gcol = wave * 64 + ni * 16 + lr;
        bv[ni] = bias[gcol]; gv[ni] = g2[gcol]; b2v[ni] = b2[gcol];
    }
    float ps[4][4], qs[4][4];
#pragma unroll
    for (int mi = 0; mi < 4; mi++)
#pragma unroll
        for (int j = 0; j < 4; j++) { ps[mi][j] = 0.f; qs[mi][j] = 0.f; }
#pragma unroll
    for (int mi = 0; mi < 4; mi++)
#pragma unroll
        for (int ni = 0; ni < 4; ni++) {
            int gcol = wave * 64 + ni * 16 + lr;
#pragma unroll
            for (int j = 0; j < 4; j++) {
                size_t idx = (size_t)srows[mi][j] * CC + gcol;
                float v = acc[mi][ni][j] + bv[ni] + x_in[idx];
                acc[mi][ni][j] = v;
                outf[idx] = v;
                ps[mi][j] += v; qs[mi][j] += v * v;
            }
        }
#pragma unroll
    for (int off = 1; off < 16; off <<= 1)
#pragma unroll
        for (int mi = 0; mi < 4; mi++)
#pragma unroll
            for (int j = 0; j < 4; j++) {
                ps[mi][j] += __shfl_xor(ps[mi][j], off);
                qs[mi][j] += __shfl_xor(qs[mi][j], off);
            }
    if (lr == 0) {
#pragma unroll
        for (int mi = 0; mi < 4; mi++)
#pragma unroll
            for (int j = 0; j < 4; j++) {
                int rl = mi * 16 + kq * 4 + j;
                rsum[wave][rl] = ps[mi][j];
                rsq[wave][rl]  = qs[mi][j];
            }
    }
    __syncthreads();
    float mean_a[4][4], rstd_a[4][4];
#pragma unroll
    for (int mi = 0; mi < 4; mi++)
#pragma unroll
        for (int j = 0; j < 4; j++) {
            int rl = mi * 16 + kq * 4 + j;
            float s  = rsum[0][rl] + rsum[1][rl] + rsum[2][rl] + rsum[3][rl];
            float s2 = rsq[0][rl] + rsq[1][rl] + rsq[2][rl] + rsq[3][rl];
            float mean = s * (1.f/256.f);
            float var  = s2 * (1.f/256.f) - mean * mean;
            mean_a[mi][j] = mean;
            rstd_a[mi][j] = rsqrtf(var + 1e-5f);
        }
#pragma unroll
    for (int mi = 0; mi < 4; mi++)
#pragma unroll
        for (int ni = 0; ni < 4; ni++) {
            int gcol = wave * 64 + ni * 16 + lr;
#pragma unroll
            for (int j = 0; j < 4; j++) {
                float m = (acc[mi][ni][j] - mean_a[mi][j]) * rstd_a[mi][j] * gv[ni] + b2v[ni];
                m_out[(size_t)srows[mi][j] * CC + gcol] = (f16)m;
            }
        }
}

// Fused MLP: out += fc2(gelu(fc1(m_in))); NO mh round-trip.
// fc1 operand-SWAPPED (A := w1, B := x); cheap sigmoid-GELU (R11-validated
// numerically; R12 showed it costs +32 VGPR unconstrained -> occupancy cliff).
// __launch_bounds__(256, 4) caps VGPR at 128 to hold R10's 4-waves/SIMD
// occupancy while keeping the cheaper GELU ALU sequence.
__global__ __launch_bounds__(256, 4) void k_mlp2(const f16* __restrict__ A,
                                                 const f16* __restrict__ w1,
                                                 const f16* __restrict__ w2,
                                                 const float* __restrict__ fb1,
                                                 const float* __restrict__ fb2,
                                                 float* __restrict__ out) {
    __shared__ char sm[49152];
    char* hbuf = sm;                 // [64][128] f16, row stride 256B, XOR-swizzled
    char* S    = sm + 16384;         // 32KB: fc1 staging (As 8K + Bs1 16K) / fc2 Bs2 32K
    f16* As  = (f16*)S;              // [2][64*32]
    f16* Bs1 = (f16*)(S + 8192);     // [2][128*32]
    f16* Bs2 = (f16*)S;              // [2][256*32]
    const int tid = threadIdx.x, wave = tid >> 6, lane = tid & 63;
    const int lr = lane & 15, kq = lane >> 4;
    const int m0 = blockIdx.x * 64;
    const int ar = tid >> 2, ac = (tid & 3) * 8;

    f32x4 acc2[4][4];
#pragma unroll
    for (int i = 0; i < 4; i++)
#pragma unroll
        for (int j = 0; j < 4; j++) acc2[i][j] = f32x4{0.f, 0.f, 0.f, 0.f};

    for (int nb = 0; nb < 8; nb++) {
        auto stage1 = [&](int b, int k0) {
            gload16(&As[b * 2048 + wave * 512], &A[(size_t)(m0 + ar) * CC + k0 + ac]);
            gload16(&Bs1[b * 4096 + wave * 512],
                    &w1[(size_t)(nb * 128 + ar) * CC + k0 + ac]);
            gload16(&Bs1[b * 4096 + 2048 + wave * 512],
                    &w1[(size_t)(nb * 128 + 64 + ar) * CC + k0 + ac]);
        };
        // ---- fc1 slice (swapped): acc1[hid frags][q frags] ----
        f32x4 acc1[2][4];
#pragma unroll
        for (int i = 0; i < 2; i++)
#pragma unroll
            for (int j = 0; j < 4; j++) acc1[i][j] = f32x4{0.f, 0.f, 0.f, 0.f};
        stage1(0, 0);
        __syncthreads();
#pragma unroll
        for (int ks = 0; ks < 8; ks++) {
            int cur = ks & 1;
            if (ks + 1 < 8) stage1(cur ^ 1, (ks + 1) * 32);
            f16x8 aw1[2], bx[4];
#pragma unroll
            for (int hi = 0; hi < 2; hi++)
                aw1[hi] = *(const f16x8*)(&Bs1[cur * 4096 +
                                               (wave * 32 + hi * 16 + lr) * 32 + kq * 8]);
#pragma unroll
            for (int qi = 0; qi < 4; qi++)
                bx[qi] = *(const f16x8*)(&As[cur * 2048 + (qi * 16 + lr) * 32 + kq * 8]);
#pragma unroll
            for (int hi = 0; hi < 2; hi++)
#pragma unroll
                for (int qi = 0; qi < 4; qi++)
                    acc1[hi][qi] = __builtin_amdgcn_mfma_f32_16x16x32_f16(
                        aw1[hi], bx[qi], acc1[hi][qi], 0, 0, 0);
            __syncthreads();
        }
        // ---- cheap gelu -> h (vectorized uint2, swizzled), stage fc2 B after ----
#pragma unroll
        for (int hi = 0; hi < 2; hi++) {
            float4 bb4 = *(const float4*)&fb1[nb * 128 + wave * 32 + hi * 16 + kq * 4];
            const float bb[4] = {bb4.x, bb4.y, bb4.z, bb4.w};
            const int hidb = wave * 64 + hi * 32 + kq * 8;   // byte = 2*hid base
#pragma unroll
            for (int qi = 0; qi < 4; qi++) {
                f16 t4[4];
#pragma unroll
                for (int j = 0; j < 4; j++) {
                    float v = acc1[hi][qi][j] + bb[j];
                    // gelu(v) = v * sigmoid(1.5957691*v + 0.0713548*v^3)
                    float e = __expf(v * (-1.5957691216f - 0.07135482f * v * v));
                    t4[j] = (f16)(v * __builtin_amdgcn_rcpf(1.f + e));
                }
                int qrow = qi * 16 + lr;
                *(uint2*)(hbuf + qrow * 256 + (hidb ^ ((qrow & 7) << 4))) =
                    *(const uint2*)t4;
            }
        }
        auto stage2 = [&](int b, int k0) {
#pragma unroll
            for (int t = 0; t < 4; t++)
                gload16(&Bs2[b * 8192 + t * 2048 + wave * 512],
                        &w2[(size_t)(t * 64 + ar) * 1024 + nb * 128 + k0 + ac]);
        };
        stage2(0, 0);
        __syncthreads();     // h visible + Bs2[0] landed (barrier drains vmcnt)
        // ---- fc2 partial: acc2[64 q rows][wave's 64 out cols] += h @ w2_nb^T ----
#pragma unroll
        for (int ks = 0; ks < 4; ks++) {
            int cur = ks & 1;
            if (ks + 1 < 4) stage2(cur ^ 1, (ks + 1) * 32);
            f16x8 ah[4], bw[4];
#pragma unroll
            for (int mi = 0; mi < 4; mi++) {
                int row = mi * 16 + lr;
                ah[mi] = *(const f16x8*)(hbuf + row * 256 +
                                         ((ks * 64 + kq * 16) ^ ((row & 7) << 4)));
            }
#pragma unroll
            for (int ni = 0; ni < 4; ni++)
                bw[ni] = *(const f16x8*)(&Bs2[cur * 8192 +
                                              (wave * 64 + ni * 16 + lr) * 32 + kq * 8]);
#pragma unroll
            for (int mi = 0; mi < 4; mi++)
#pragma unroll
                for (int ni = 0; ni < 4; ni++)
                    acc2[mi][ni] = __builtin_amdgcn_mfma_f32_16x16x32_f16(
                        ah[mi], bw[ni], acc2[mi][ni], 0, 0, 0);
            __syncthreads();
        }
    }

    // ---- epilogue: out += acc2 + fb2 (coalesced 64B f32 segments) ----
#pragma unroll
    for (int mi = 0; mi < 4; mi++)
#pragma unroll
        for (int ni = 0; ni < 4; ni++)
#pragma unroll
            for (int j = 0; j < 4; j++) {
                int qrow = m0 + mi * 16 + kq * 4 + j;
                int oc = wave * 64 + ni * 16 + lr;
                size_t idx = (size_t)qrow * CC + oc;
                out[idx] = out[idx] + acc2[mi][ni][j] + fb2[oc];
            }
}

// MFMA attention: one wave per (window, head). S^T = mfma(K,Q); in-register
// softmax over keys; j-packed b64 swizzled LDS P-transpose; O^T = mfma(V^T, P);
// swizzled O-transpose -> 4 coalesced stores. 17.3KB LDS.
__global__ __launch_bounds__(64) void k_attn(const f16* __restrict__ q,
                                             const f16* __restrict__ kk,
                                             const f16* __restrict__ vv,
                                             const float* __restrict__ rpb,
                                             f16* __restrict__ aw, int winbase) {
    __shared__ char sm[17408];      // P[64][64] 8KB | VT[32][64] 4KB | O[64][32] 4KB | rl 900B
    float* rl = (float*)(sm + 16384);
    const int wl = blockIdx.x >> 3, h = blockIdx.x & 7;
    const int lane = threadIdx.x;
    const int lr = lane & 15, kq = lane >> 4;
    const size_t base = ((size_t)wl * 8 + h) * 2048;

    for (int i = lane; i < 225; i += 64) rl[i] = rpb[i * 8 + h];

    {
        f16 vr[32];
        const uint4* vs = (const uint4*)(vv + base + lane * 32);
#pragma unroll
        for (int c = 0; c < 4; c++) *(uint4*)&vr[c * 8] = vs[c];
#pragma unroll
        for (int d = 0; d < 32; d++)
            *(f16*)(sm + 8192 + d * 128 + ((lane * 2) ^ ((d & 7) << 4))) = vr[d];
    }

    f16x8 kf[4], qf[4];
#pragma unroll
    for (int t = 0; t < 4; t++) {
        kf[t] = *(const f16x8*)(kk + base + (size_t)(t * 16 + lr) * 32 + kq * 8);
        qf[t] = *(const f16x8*)(q  + base + (size_t)(t * 16 + lr) * 32 + kq * 8);
    }

    f32x4 st[4][4];
#pragma unroll
    for (int mi = 0; mi < 4; mi++)
#pragma unroll
        for (int ni = 0; ni < 4; ni++) st[mi][ni] = f32x4{0.f, 0.f, 0.f, 0.f};
#pragma unroll
    for (int mi = 0; mi < 4; mi++)
#pragma unroll
        for (int ni = 0; ni < 4; ni++)
            st[mi][ni] = __builtin_amdgcn_mfma_f32_16x16x32_f16(kf[mi], qf[ni], st[mi][ni], 0, 0, 0);

    __syncthreads();

    const int gwin = (winbase + wl) & 63;
    const int wh = gwin >> 3, ww = gwin & 7;
    int yq[4], xq[4], rq[4];
#pragma unroll
    for (int ni = 0; ni < 4; ni++) {
        int qq = ni * 16 + lr;
        yq[ni] = qq >> 3; xq[ni] = qq & 7;
        rq[ni] = ((wh < 7) ? 0 : ((yq[ni] < 4) ? 1 : 2)) * 3 +
                 ((ww < 7) ? 0 : ((xq[ni] < 4) ? 1 : 2));
    }
#pragma unroll
    for (int mi = 0; mi < 4; mi++)
#pragma unroll
        for (int j = 0; j < 4; j++) {
            int kt = mi * 16 + kq * 4 + j;
            int yk = kt >> 3, xk = kt & 7;
            int rk = ((wh < 7) ? 0 : ((yk < 4) ? 1 : 2)) * 3 +
                     ((ww < 7) ? 0 : ((xk < 4) ? 1 : 2));
#pragma unroll
            for (int ni = 0; ni < 4; ni++) {
                float b = rl[(yq[ni] - yk + 7) * 15 + (xq[ni] - xk + 7)];
                if (rq[ni] != rk) b -= 100.f;
                st[mi][ni][j] += b;
            }
        }

    float mx[4] = {-1e30f, -1e30f, -1e30f, -1e30f};
#pragma unroll
    for (int mi = 0; mi < 4; mi++)
#pragma unroll
        for (int ni = 0; ni < 4; ni++)
#pragma unroll
            for (int j = 0; j < 4; j++) mx[ni] = fmaxf(mx[ni], st[mi][ni][j]);
#pragma unroll
    for (int ni = 0; ni < 4; ni++) {
        mx[ni] = fmaxf(mx[ni], __shfl_xor(mx[ni], 16));
        mx[ni] = fmaxf(mx[ni], __shfl_xor(mx[ni], 32));
    }
    float sme[4] = {0.f, 0.f, 0.f, 0.f};
#pragma unroll
    for (int mi = 0; mi < 4; mi++)
#pragma unroll
        for (int ni = 0; ni < 4; ni++)
#pragma unroll
            for (int j = 0; j < 4; j++) {
                float e = __expf(st[mi][ni][j] - mx[ni]);
                st[mi][ni][j] = e;
                sme[ni] += e;
            }
#pragma unroll
    for (int ni = 0; ni < 4; ni++) {
        sme[ni] += __shfl_xor(sme[ni], 16);
        sme[ni] += __shfl_xor(sme[ni], 32);
    }
    float inv[4];
#pragma unroll
    for (int ni = 0; ni < 4; ni++) inv[ni] = 1.f / sme[ni];

#pragma unroll
    for (int mi = 0; mi < 4; mi++)
#pragma unroll
        for (int ni = 0; ni < 4; ni++) {
            f16 t4[4];
#pragma unroll
            for (int j = 0; j < 4; j++) t4[j] = (f16)st[mi][ni][j];
            int qq = ni * 16 + lr;
            *(uint2*)(sm + qq * 128 + ((mi * 32 + kq * 8) ^ ((qq & 7) << 4))) =
                *(const uint2*)t4;
        }
    __syncthreads();

    f32x4 oa[2][4];
#pragma unroll
    for (int mi2 = 0; mi2 < 2; mi2++)
#pragma unroll
        for (int ni = 0; ni < 4; ni++) oa[mi2][ni] = f32x4{0.f, 0.f, 0.f, 0.f};
#pragma unroll
    for (int ks = 0; ks < 2; ks++) {
        f16x8 va[2], pb[4];
#pragma unroll
        for (int mi2 = 0; mi2 < 2; mi2++) {
            int row = mi2 * 16 + lr;
            va[mi2] = *(const f16x8*)(sm + 8192 + row * 128 +
                                      ((ks * 64 + kq * 16) ^ ((row & 7) << 4)));
        }
#pragma unroll
        for (int ni = 0; ni < 4; ni++) {
            int qq = ni * 16 + lr;
            pb[ni] = *(const f16x8*)(sm + qq * 128 +
                                     ((ks * 64 + kq * 16) ^ ((qq & 7) << 4)));
        }
#pragma unroll
        for (int mi2 = 0; mi2 < 2; mi2++)
#pragma unroll
            for (int ni = 0; ni < 4; ni++)
                oa[mi2][ni] = __builtin_amdgcn_mfma_f32_16x16x32_f16(va[mi2], pb[ni], oa[mi2][ni], 0, 0, 0);
    }

#pragma unroll
    for (int mi2 = 0; mi2 < 2; mi2++)
#pragma unroll
        for (int ni = 0; ni < 4; ni++) {
            f16 t4[4];
#pragma unroll
            for (int j = 0; j < 4; j++) t4[j] = (f16)(oa[mi2][ni][j] * inv[ni]);
            int qq = ni * 16 + lr;
            *(uint2*)(sm + 12288 + qq * 64 + ((mi2 * 32 + kq * 8) ^ ((qq & 3) << 4))) =
                *(const uint2*)t4;
        }
    __syncthreads();

    f16* dst = aw + ((size_t)(wl * 64 + lane)) * CC + h * 32;
#pragma unroll
    for (int c = 0; c < 4; c++) {
        uint4 wv = *(const uint4*)(sm + 12288 + lane * 64 +
                                   ((c * 16) ^ ((lane & 3) << 4)));
        *(uint4*)(dst + c * 8) = wv;
    }
}

extern "C" void kernel_launch(void* const* d_in, const int* in_sizes, int n_in,
                              void* d_out, int out_size, void* d_ws, size_t ws_size,
                              hipStream_t stream) {
    (void)in_sizes; (void)n_in; (void)out_size; (void)ws_size;
    const float* x      = (const float*)d_in[0];
    const float* g1     = (const float*)d_in[1];
    const float* b1     = (const float*)d_in[2];
    const float* qkv_w  = (const float*)d_in[3];
    const float* qkv_b  = (const float*)d_in[4];
    const float* rpb    = (const float*)d_in[5];
    const float* proj_w = (const float*)d_in[6];
    const float* proj_b = (const float*)d_in[7];
    const float* g2     = (const float*)d_in[8];
    const float* b2     = (const float*)d_in[9];
    const float* fc1_w  = (const float*)d_in[10];
    const float* fc1_b  = (const float*)d_in[11];
    const float* fc2_w  = (const float*)d_in[12];
    const float* fc2_b  = (const float*)d_in[13];
    float* out = (float*)d_out;
    char* ws = (char*)d_ws;
    f16* wq = (f16*)(ws + OFF_WQ);
    f16* wp = (f16*)(ws + OFF_WP);
    f16* w1 = (f16*)(ws + OFF_W1);
    f16* w2 = (f16*)(ws + OFF_W2);
    f16* awb = (f16*)(ws + OFF_R1);
    static constexpr size_t QSZ = (size_t)CWINS * 8 * 64 * 32 * 2; // 16,777,216 B
    f16* hwin = (f16*)(ws + OFF_R2);
    f16* qb   = (f16*)(ws + OFF_R2 + QSZ);
    f16* kb   = (f16*)(ws + OFF_R2 + 2 * QSZ);
    f16* vb   = (f16*)(ws + OFF_R2 + 3 * QSZ);
    f16* m_in = (f16*)(ws + OFF_R2);

    k_cvt<<<768, 256, 0, stream>>>(qkv_w, wq, 768 * 256);
    k_cvt<<<256, 256, 0, stream>>>(proj_w, wp, 256 * 256);
    k_cvt<<<1024, 256, 0, stream>>>(fc1_w, w1, 1024 * 256);
    k_cvt<<<1024, 256, 0, stream>>>(fc2_w, w2, 1024 * 256);

    // --- attention phase: per chunk LN1 -> QKV -> attn (writes full AW) ---
    for (int c = 0; c < ACH; c++) {
        k_ln<<<AROWS / 4, 256, 0, stream>>>(x, g1, b1, hwin, c * AROWS);
        k_qkv<<<dim3(AROWS / 128, 6), 256, 0, stream>>>(
            hwin, wq, qkv_b, qb, kb, vb);
        k_attn<<<CWINS * 8, 64, 0, stream>>>(
            qb, kb, vb, rpb, awb + (size_t)c * AROWS * CC, c * CWINS);
    }
    // proj over full M, fused un-shift + residual -> out, fused LN2 -> m_in
    k_proj<<<ROWS / 64, 256, 0, stream>>>(awb, wp, proj_b, x, out, m_in, g2, b2);

    // --- fused MLP (no mh round-trip), single launch over full M ---
    k_mlp2<<<ROWS / 64, 256, 0, stream>>>(m_in, w1, w2, fc1_b, fc2_b, out);
}

// Round 14
// 627.208 us; speedup vs baseline: 1.1723x; 1.1212x over previous
//
#include <hip/hip_runtime.h>
#include <hip/hip_bf16.h>
#include <stdint.h>

using f16 = _Float16;
typedef _Float16 f16x8 __attribute__((ext_vector_type(8)));
typedef float f32x4 __attribute__((ext_vector_type(4)));

static constexpr int HW = 4096;        // H*W
static constexpr int CC = 256;         // channels
static constexpr int ROWS = 131072;    // B*H*W
static constexpr int ACH = 4;          // attention-phase chunks
static constexpr int AROWS = ROWS / ACH;      // 32768 rows / chunk
static constexpr int CWINS = AROWS / 64;      // 512 windows / chunk
static constexpr int SSH = 4;          // shift

// workspace layout (bytes)
static constexpr size_t OFF_WQ = 0;                               // qkv_w f16  768*256
static constexpr size_t OFF_WP = OFF_WQ + (size_t)768*256*2;      // proj_w f16 256*256
static constexpr size_t OFF_W1 = OFF_WP + (size_t)256*256*2;      // fc1_w f16  1024*256
static constexpr size_t OFF_W2 = OFF_W1 + (size_t)1024*256*2;     // fc2_w f16  256*1024
static constexpr size_t OFF_R1 = OFF_W2 + (size_t)256*1024*2;     // 67,108,864 B region
static constexpr size_t OFF_R2 = OFF_R1 + (size_t)ROWS*CC*2;      // 67,108,864 B region
// R1: AW full (131072x256 f16). R2: hwin chunk + Q + K + V -> then m_in full.

__device__ __forceinline__ void gload16(void* lds, const void* g) {
    __builtin_amdgcn_global_load_lds(
        (const __attribute__((address_space(1))) unsigned int*)g,
        (__attribute__((address_space(3))) unsigned int*)lds, 16, 0, 0);
}

__global__ void k_cvt(const float* __restrict__ s, f16* __restrict__ d, int n) {
    int i = blockIdx.x * 256 + threadIdx.x;
    if (i < n) d[i] = (f16)s[i];
}

// LayerNorm over C=256, dest row (windowed+rolled) gathers from source row of x.
__global__ __launch_bounds__(256) void k_ln(const float* __restrict__ x,
                                            const float* __restrict__ g,
                                            const float* __restrict__ be,
                                            f16* __restrict__ dst, int rowbase) {
    int lrow = blockIdx.x * 4 + (threadIdx.x >> 6);
    int grow = rowbase + lrow;
    int lane = threadIdx.x & 63;
    int n = grow & 63, win = (grow >> 6) & 63, b = grow >> 12;
    int hh  = ((win >> 3) << 3) | (n >> 3);
    int wwc = ((win & 7) << 3) | (n & 7);
    int ho = (hh + SSH) & 63, wo = (wwc + SSH) & 63;
    size_t srow = (size_t)b * HW + ho * 64 + wo;
    float4 v = ((const float4*)(x + srow * CC))[lane];
    float s  = v.x + v.y + v.z + v.w;
    float s2 = v.x*v.x + v.y*v.y + v.z*v.z + v.w*v.w;
#pragma unroll
    for (int off = 32; off; off >>= 1) { s += __shfl_xor(s, off); s2 += __shfl_xor(s2, off); }
    float mean = s * (1.f/256.f);
    float rstd = rsqrtf(s2 * (1.f/256.f) - mean*mean + 1e-5f);
    float4 gv = ((const float4*)g)[lane];
    float4 bv = ((const float4*)be)[lane];
    f16 ob[4];
    ob[0] = (f16)((v.x-mean)*rstd*gv.x + bv.x);
    ob[1] = (f16)((v.y-mean)*rstd*gv.y + bv.y);
    ob[2] = (f16)((v.z-mean)*rstd*gv.z + bv.z);
    ob[3] = (f16)((v.w-mean)*rstd*gv.w + bv.w);
    *(uint2*)(dst + (size_t)lrow * CC + lane * 4) = *(const uint2*)ob;
}

// QKV GEMM: out = A * Wt^T (+bias), 128x128 tile, BK=32, 2-phase double-buffer.
__global__ __launch_bounds__(256) void k_qkv(const f16* __restrict__ A,
                                             const f16* __restrict__ Wt,
                                             const float* __restrict__ bias,
                                             f16* __restrict__ q, f16* __restrict__ kk,
                                             f16* __restrict__ vv) {
    __shared__ f16 As[2][128 * 32];
    __shared__ f16 Bs[2][128 * 32];
    const int tid = threadIdx.x;
    const int m0 = blockIdx.x * 128, n0 = blockIdx.y * 128;
    const int wave = tid >> 6, lane = tid & 63;
    const int wm = (wave >> 1) * 64, wn = (wave & 1) * 64;
    const int lr = lane & 15, kq = lane >> 4;
    const int i0 = wave * 128 + lane;
    const int r0 = i0 >> 2, c0 = (i0 & 3) * 8;
    const int i1 = i0 + 64;
    const int r1 = i1 >> 2, c1 = (i1 & 3) * 8;
    const int base0 = wave * 1024, base1 = base0 + 512;

    auto stage = [&](int b, int k0) {
        gload16(&As[b][base0], &A [(size_t)(m0 + r0) * CC + k0 + c0]);
        gload16(&Bs[b][base0], &Wt[(size_t)(n0 + r0) * CC + k0 + c0]);
        gload16(&As[b][base1], &A [(size_t)(m0 + r1) * CC + k0 + c1]);
        gload16(&Bs[b][base1], &Wt[(size_t)(n0 + r1) * CC + k0 + c1]);
    };

    f32x4 acc[4][4];
#pragma unroll
    for (int i = 0; i < 4; i++)
#pragma unroll
        for (int j = 0; j < 4; j++) acc[i][j] = f32x4{0.f, 0.f, 0.f, 0.f};

    stage(0, 0);
    __syncthreads();
    for (int s = 0; s < 8; s++) {
        int cur = s & 1;
        if (s + 1 < 8) stage(cur ^ 1, (s + 1) * 32);
        f16x8 af[4], bfv[4];
#pragma unroll
        for (int i = 0; i < 4; i++) {
            af[i]  = *(const f16x8*)(&As[cur][(wm + i * 16 + lr) * 32 + kq * 8]);
            bfv[i] = *(const f16x8*)(&Bs[cur][(wn + i * 16 + lr) * 32 + kq * 8]);
        }
#pragma unroll
        for (int mi = 0; mi < 4; mi++)
#pragma unroll
            for (int ni = 0; ni < 4; ni++)
                acc[mi][ni] = __builtin_amdgcn_mfma_f32_16x16x32_f16(af[mi], bfv[ni], acc[mi][ni], 0, 0, 0);
        __syncthreads();
    }

#pragma unroll
    for (int mi = 0; mi < 4; mi++)
#pragma unroll
        for (int ni = 0; ni < 4; ni++)
#pragma unroll
            for (int j = 0; j < 4; j++) {
                int lrow = m0 + wm + mi * 16 + kq * 4 + j;   // C/D: row=(lane>>4)*4+j
                int gcol = n0 + wn + ni * 16 + lr;           //      col=lane&15
                float val = acc[mi][ni][j] + bias[gcol];
                int s = gcol >> 8, h2 = (gcol >> 5) & 7, d = gcol & 31;
                if (s == 0) val *= 0.1767766952966369f;  // HD^-0.5
                f16* dst = (s == 0) ? q : (s == 1 ? kk : vv);
                int winl = lrow >> 6, n = lrow & 63;
                dst[(((size_t)winl * 8 + h2) * 64 + n) * 32 + d] = (f16)val;
            }
}

// proj GEMM, tile 64 rows x 256 cols (full row per block), 4 waves (1x4 of 64x64).
// Epilogue: + proj bias, + un-shift scatter + shortcut residual -> d_out (f32),
// then in-block LayerNorm2 over the complete 256-wide row -> m_in (f16).
__global__ __launch_bounds__(256, 2) void k_proj(const f16* __restrict__ A,
                                                 const f16* __restrict__ Wt,
                                                 const float* __restrict__ bias,
                                                 const float* __restrict__ x_in,
                                                 float* __restrict__ outf,
                                                 f16* __restrict__ m_out,
                                                 const float* __restrict__ g2,
                                                 const float* __restrict__ b2) {
    __shared__ f16 As[2][64 * 32];
    __shared__ f16 Bs[2][256 * 32];
    __shared__ float rsum[4][64];
    __shared__ float rsq[4][64];
    const int tid = threadIdx.x;
    const int m0 = blockIdx.x * 64;
    const int wave = tid >> 6, lane = tid & 63;
    const int lr = lane & 15, kq = lane >> 4;
    const int ar = tid >> 2, ac = (tid & 3) * 8;   // A stage: 256 chunks, 1/thread

    auto stage = [&](int b, int k0) {
        gload16(&As[b][wave * 512], &A[(size_t)(m0 + ar) * CC + k0 + ac]);
#pragma unroll
        for (int r = 0; r < 4; r++)
            gload16(&Bs[b][(r * 256 + wave * 64) * 8],
                    &Wt[(size_t)(r * 64 + ar) * CC + k0 + ac]);
    };

    f32x4 acc[4][4];
#pragma unroll
    for (int i = 0; i < 4; i++)
#pragma unroll
        for (int j = 0; j < 4; j++) acc[i][j] = f32x4{0.f, 0.f, 0.f, 0.f};

    stage(0, 0);
    __syncthreads();
    for (int s = 0; s < 8; s++) {
        int cur = s & 1;
        if (s + 1 < 8) stage(cur ^ 1, (s + 1) * 32);
        f16x8 af[4], bfv[4];
#pragma unroll
        for (int i = 0; i < 4; i++) {
            af[i]  = *(const f16x8*)(&As[cur][(i * 16 + lr) * 32 + kq * 8]);
            bfv[i] = *(const f16x8*)(&Bs[cur][(wave * 64 + i * 16 + lr) * 32 + kq * 8]);
        }
#pragma unroll
        for (int mi = 0; mi < 4; mi++)
#pragma unroll
            for (int ni = 0; ni < 4; ni++)
                acc[mi][ni] = __builtin_amdgcn_mfma_f32_16x16x32_f16(af[mi], bfv[ni], acc[mi][ni], 0, 0, 0);
        __syncthreads();
    }

    // ---- epilogue: x2 = proj + bias + shortcut (per un-shift scatter) ----
    int srows[4][4];
#pragma unroll
    for (int mi = 0; mi < 4; mi++)
#pragma unroll
        for (int j = 0; j < 4; j++) {
            int row = m0 + mi * 16 + kq * 4 + j;       // windowed-order global row
            int n = row & 63, win = (row >> 6) & 63, b = row >> 12;
            int hh  = ((win >> 3) << 3) | (n >> 3);
            int wwc = ((win & 7) << 3) | (n & 7);
            int ho = (hh + SSH) & 63, wo = (wwc + SSH) & 63;
            srows[mi][j] = b * HW + ho * 64 + wo;
        }
    float bv[4], gv[4], b2v[4];
#pragma unroll
    for (int ni = 0; ni < 4; ni++) {
        int gcol = wave * 64 + ni * 16 + lr;
        bv[ni] = bias[gcol]; gv[ni] = g2[gcol]; b2v[ni] = b2[gcol];
    }
    float ps[4][4], qs[4][4];
#pragma unroll
    for (int mi = 0; mi < 4; mi++)
#pragma unroll
        for (int j = 0; j < 4; j++) { ps[mi][j] = 0.f; qs[mi][j] = 0.f; }
#pragma unroll
    for (int mi = 0; mi < 4; mi++)
#pragma unroll
        for (int ni = 0; ni < 4; ni++) {
            int gcol = wave * 64 + ni * 16 + lr;
#pragma unroll
            for (int j = 0; j < 4; j++) {
                size_t idx = (size_t)srows[mi][j] * CC + gcol;
                float v = acc[mi][ni][j] + bv[ni] + x_in[idx];
                acc[mi][ni][j] = v;
                outf[idx] = v;
                ps[mi][j] += v; qs[mi][j] += v * v;
            }
        }
#pragma unroll
    for (int off = 1; off < 16; off <<= 1)
#pragma unroll
        for (int mi = 0; mi < 4; mi++)
#pragma unroll
            for (int j = 0; j < 4; j++) {
                ps[mi][j] += __shfl_xor(ps[mi][j], off);
                qs[mi][j] += __shfl_xor(qs[mi][j], off);
            }
    if (lr == 0) {
#pragma unroll
        for (int mi = 0; mi < 4; mi++)
#pragma unroll
            for (int j = 0; j < 4; j++) {
                int rl = mi * 16 + kq * 4 + j;
                rsum[wave][rl] = ps[mi][j];
                rsq[wave][rl]  = qs[mi][j];
            }
    }
    __syncthreads();
    float mean_a[4][4], rstd_a[4][4];
#pragma unroll
    for (int mi = 0; mi < 4; mi++)
#pragma unroll
        for (int j = 0; j < 4; j++) {
            int rl = mi * 16 + kq * 4 + j;
            float s  = rsum[0][rl] + rsum[1][rl] + rsum[2][rl] + rsum[3][rl];
            float s2 = rsq[0][rl] + rsq[1][rl] + rsq[2][rl] + rsq[3][rl];
            float mean = s * (1.f/256.f);
            float var  = s2 * (1.f/256.f) - mean * mean;
            mean_a[mi][j] = mean;
            rstd_a[mi][j] = rsqrtf(var + 1e-5f);
        }
#pragma unroll
    for (int mi = 0; mi < 4; mi++)
#pragma unroll
        for (int ni = 0; ni < 4; ni++) {
            int gcol = wave * 64 + ni * 16 + lr;
#pragma unroll
            for (int j = 0; j < 4; j++) {
                float m = (acc[mi][ni][j] - mean_a[mi][j]) * rstd_a[mi][j] * gv[ni] + b2v[ni];
                m_out[(size_t)srows[mi][j] * CC + gcol] = (f16)m;
            }
        }
}

// Fused MLP: out += fc2(gelu(fc1(m_in))); NO mh round-trip.
// fc1 operand-SWAPPED (A := w1, B := x) so the j-dim walks consecutive hid ->
// gelu'd h written as aligned uint2 into swizzled h[q][hid].
// Tanh-GELU (R10 champion): 116 VGPR / 22% occupancy — cheap-GELU variants
// (R12/R13) inflate VGPR to 148 and halve occupancy for a net loss.
// fc2: h swizzled b128 reads, acc2 persistent across nb (K-loop accumulator).
__global__ __launch_bounds__(256) void k_mlp2(const f16* __restrict__ A,
                                              const f16* __restrict__ w1,
                                              const f16* __restrict__ w2,
                                              const float* __restrict__ fb1,
                                              const float* __restrict__ fb2,
                                              float* __restrict__ out) {
    __shared__ char sm[49152];
    char* hbuf = sm;                 // [64][128] f16, row stride 256B, XOR-swizzled
    char* S    = sm + 16384;         // 32KB: fc1 staging (As 8K + Bs1 16K) / fc2 Bs2 32K
    f16* As  = (f16*)S;              // [2][64*32]
    f16* Bs1 = (f16*)(S + 8192);     // [2][128*32]
    f16* Bs2 = (f16*)S;              // [2][256*32]
    const int tid = threadIdx.x, wave = tid >> 6, lane = tid & 63;
    const int lr = lane & 15, kq = lane >> 4;
    const int m0 = blockIdx.x * 64;
    const int ar = tid >> 2, ac = (tid & 3) * 8;

    f32x4 acc2[4][4];
#pragma unroll
    for (int i = 0; i < 4; i++)
#pragma unroll
        for (int j = 0; j < 4; j++) acc2[i][j] = f32x4{0.f, 0.f, 0.f, 0.f};

    for (int nb = 0; nb < 8; nb++) {
        auto stage1 = [&](int b, int k0) {
            gload16(&As[b * 2048 + wave * 512], &A[(size_t)(m0 + ar) * CC + k0 + ac]);
            gload16(&Bs1[b * 4096 + wave * 512],
                    &w1[(size_t)(nb * 128 + ar) * CC + k0 + ac]);
            gload16(&Bs1[b * 4096 + 2048 + wave * 512],
                    &w1[(size_t)(nb * 128 + 64 + ar) * CC + k0 + ac]);
        };
        // ---- fc1 slice (swapped): acc1[hid frags][q frags] ----
        f32x4 acc1[2][4];
#pragma unroll
        for (int i = 0; i < 2; i++)
#pragma unroll
            for (int j = 0; j < 4; j++) acc1[i][j] = f32x4{0.f, 0.f, 0.f, 0.f};
        stage1(0, 0);
        __syncthreads();
#pragma unroll
        for (int ks = 0; ks < 8; ks++) {
            int cur = ks & 1;
            if (ks + 1 < 8) stage1(cur ^ 1, (ks + 1) * 32);
            f16x8 aw1[2], bx[4];
#pragma unroll
            for (int hi = 0; hi < 2; hi++)
                aw1[hi] = *(const f16x8*)(&Bs1[cur * 4096 +
                                               (wave * 32 + hi * 16 + lr) * 32 + kq * 8]);
#pragma unroll
            for (int qi = 0; qi < 4; qi++)
                bx[qi] = *(const f16x8*)(&As[cur * 2048 + (qi * 16 + lr) * 32 + kq * 8]);
#pragma unroll
            for (int hi = 0; hi < 2; hi++)
#pragma unroll
                for (int qi = 0; qi < 4; qi++)
                    acc1[hi][qi] = __builtin_amdgcn_mfma_f32_16x16x32_f16(
                        aw1[hi], bx[qi], acc1[hi][qi], 0, 0, 0);
            __syncthreads();
        }
        // ---- gelu -> h (vectorized uint2, swizzled), stage fc2 B after ----
#pragma unroll
        for (int hi = 0; hi < 2; hi++) {
            float4 bb4 = *(const float4*)&fb1[nb * 128 + wave * 32 + hi * 16 + kq * 4];
            const float bb[4] = {bb4.x, bb4.y, bb4.z, bb4.w};
            const int hidb = wave * 64 + hi * 32 + kq * 8;   // byte = 2*hid base
#pragma unroll
            for (int qi = 0; qi < 4; qi++) {
                f16 t4[4];
#pragma unroll
                for (int j = 0; j < 4; j++) {
                    float v = acc1[hi][qi][j] + bb[j];
                    float z = 0.7978845608028654f * (v + 0.044715f * v * v * v);
                    float t = 1.f - 2.f / (__expf(2.f * z) + 1.f);
                    t4[j] = (f16)(0.5f * v * (1.f + t));
                }
                int qrow = qi * 16 + lr;
                *(uint2*)(hbuf + qrow * 256 + (hidb ^ ((qrow & 7) << 4))) =
                    *(const uint2*)t4;
            }
        }
        auto stage2 = [&](int b, int k0) {
#pragma unroll
            for (int t = 0; t < 4; t++)
                gload16(&Bs2[b * 8192 + t * 2048 + wave * 512],
                        &w2[(size_t)(t * 64 + ar) * 1024 + nb * 128 + k0 + ac]);
        };
        stage2(0, 0);
        __syncthreads();     // h visible + Bs2[0] landed (barrier drains vmcnt)
        // ---- fc2 partial: acc2[64 q rows][wave's 64 out cols] += h @ w2_nb^T ----
#pragma unroll
        for (int ks = 0; ks < 4; ks++) {
            int cur = ks & 1;
            if (ks + 1 < 4) stage2(cur ^ 1, (ks + 1) * 32);
            f16x8 ah[4], bw[4];
#pragma unroll
            for (int mi = 0; mi < 4; mi++) {
                int row = mi * 16 + lr;
                ah[mi] = *(const f16x8*)(hbuf + row * 256 +
                                         ((ks * 64 + kq * 16) ^ ((row & 7) << 4)));
            }
#pragma unroll
            for (int ni = 0; ni < 4; ni++)
                bw[ni] = *(const f16x8*)(&Bs2[cur * 8192 +
                                              (wave * 64 + ni * 16 + lr) * 32 + kq * 8]);
#pragma unroll
            for (int mi = 0; mi < 4; mi++)
#pragma unroll
                for (int ni = 0; ni < 4; ni++)
                    acc2[mi][ni] = __builtin_amdgcn_mfma_f32_16x16x32_f16(
                        ah[mi], bw[ni], acc2[mi][ni], 0, 0, 0);
            __syncthreads();
        }
    }

    // ---- epilogue: out += acc2 + fb2 (coalesced 64B f32 segments) ----
#pragma unroll
    for (int mi = 0; mi < 4; mi++)
#pragma unroll
        for (int ni = 0; ni < 4; ni++)
#pragma unroll
            for (int j = 0; j < 4; j++) {
                int qrow = m0 + mi * 16 + kq * 4 + j;
                int oc = wave * 64 + ni * 16 + lr;
                size_t idx = (size_t)qrow * CC + oc;
                out[idx] = out[idx] + acc2[mi][ni][j] + fb2[oc];
            }
}

// MFMA attention: one wave per (window, head). S^T = mfma(K,Q); in-register
// softmax over keys; j-packed b64 swizzled LDS P-transpose; O^T = mfma(V^T, P);
// swizzled O-transpose -> 4 coalesced stores. 17.3KB LDS.
__global__ __launch_bounds__(64) void k_attn(const f16* __restrict__ q,
                                             const f16* __restrict__ kk,
                                             const f16* __restrict__ vv,
                                             const float* __restrict__ rpb,
                                             f16* __restrict__ aw, int winbase) {
    __shared__ char sm[17408];      // P[64][64] 8KB | VT[32][64] 4KB | O[64][32] 4KB | rl 900B
    float* rl = (float*)(sm + 16384);
    const int wl = blockIdx.x >> 3, h = blockIdx.x & 7;
    const int lane = threadIdx.x;
    const int lr = lane & 15, kq = lane >> 4;
    const size_t base = ((size_t)wl * 8 + h) * 2048;

    for (int i = lane; i < 225; i += 64) rl[i] = rpb[i * 8 + h];

    {
        f16 vr[32];
        const uint4* vs = (const uint4*)(vv + base + lane * 32);
#pragma unroll
        for (int c = 0; c < 4; c++) *(uint4*)&vr[c * 8] = vs[c];
#pragma unroll
        for (int d = 0; d < 32; d++)
            *(f16*)(sm + 8192 + d * 128 + ((lane * 2) ^ ((d & 7) << 4))) = vr[d];
    }

    f16x8 kf[4], qf[4];
#pragma unroll
    for (int t = 0; t < 4; t++) {
        kf[t] = *(const f16x8*)(kk + base + (size_t)(t * 16 + lr) * 32 + kq * 8);
        qf[t] = *(const f16x8*)(q  + base + (size_t)(t * 16 + lr) * 32 + kq * 8);
    }

    f32x4 st[4][4];
#pragma unroll
    for (int mi = 0; mi < 4; mi++)
#pragma unroll
        for (int ni = 0; ni < 4; ni++) st[mi][ni] = f32x4{0.f, 0.f, 0.f, 0.f};
#pragma unroll
    for (int mi = 0; mi < 4; mi++)
#pragma unroll
        for (int ni = 0; ni < 4; ni++)
            st[mi][ni] = __builtin_amdgcn_mfma_f32_16x16x32_f16(kf[mi], qf[ni], st[mi][ni], 0, 0, 0);

    __syncthreads();

    const int gwin = (winbase + wl) & 63;
    const int wh = gwin >> 3, ww = gwin & 7;
    int yq[4], xq[4], rq[4];
#pragma unroll
    for (int ni = 0; ni < 4; ni++) {
        int qq = ni * 16 + lr;
        yq[ni] = qq >> 3; xq[ni] = qq & 7;
        rq[ni] = ((wh < 7) ? 0 : ((yq[ni] < 4) ? 1 : 2)) * 3 +
                 ((ww < 7) ? 0 : ((xq[ni] < 4) ? 1 : 2));
    }
#pragma unroll
    for (int mi = 0; mi < 4; mi++)
#pragma unroll
        for (int j = 0; j < 4; j++) {
            int kt = mi * 16 + kq * 4 + j;
            int yk = kt >> 3, xk = kt & 7;
            int rk = ((wh < 7) ? 0 : ((yk < 4) ? 1 : 2)) * 3 +
                     ((ww < 7) ? 0 : ((xk < 4) ? 1 : 2));
#pragma unroll
            for (int ni = 0; ni < 4; ni++) {
                float b = rl[(yq[ni] - yk + 7) * 15 + (xq[ni] - xk + 7)];
                if (rq[ni] != rk) b -= 100.f;
                st[mi][ni][j] += b;
            }
        }

    float mx[4] = {-1e30f, -1e30f, -1e30f, -1e30f};
#pragma unroll
    for (int mi = 0; mi < 4; mi++)
#pragma unroll
        for (int ni = 0; ni < 4; ni++)
#pragma unroll
            for (int j = 0; j < 4; j++) mx[ni] = fmaxf(mx[ni], st[mi][ni][j]);
#pragma unroll
    for (int ni = 0; ni < 4; ni++) {
        mx[ni] = fmaxf(mx[ni], __shfl_xor(mx[ni], 16));
        mx[ni] = fmaxf(mx[ni], __shfl_xor(mx[ni], 32));
    }
    float sme[4] = {0.f, 0.f, 0.f, 0.f};
#pragma unroll
    for (int mi = 0; mi < 4; mi++)
#pragma unroll
        for (int ni = 0; ni < 4; ni++)
#pragma unroll
            for (int j = 0; j < 4; j++) {
                float e = __expf(st[mi][ni][j] - mx[ni]);
                st[mi][ni][j] = e;
                sme[ni] += e;
            }
#pragma unroll
    for (int ni = 0; ni < 4; ni++) {
        sme[ni] += __shfl_xor(sme[ni], 16);
        sme[ni] += __shfl_xor(sme[ni], 32);
    }
    float inv[4];
#pragma unroll
    for (int ni = 0; ni < 4; ni++) inv[ni] = 1.f / sme[ni];

#pragma unroll
    for (int mi = 0; mi < 4; mi++)
#pragma unroll
        for (int ni = 0; ni < 4; ni++) {
            f16 t4[4];
#pragma unroll
            for (int j = 0; j < 4; j++) t4[j] = (f16)st[mi][ni][j];
            int qq = ni * 16 + lr;
            *(uint2*)(sm + qq * 128 + ((mi * 32 + kq * 8) ^ ((qq & 7) << 4))) =
                *(const uint2*)t4;
        }
    __syncthreads();

    f32x4 oa[2][4];
#pragma unroll
    for (int mi2 = 0; mi2 < 2; mi2++)
#pragma unroll
        for (int ni = 0; ni < 4; ni++) oa[mi2][ni] = f32x4{0.f, 0.f, 0.f, 0.f};
#pragma unroll
    for (int ks = 0; ks < 2; ks++) {
        f16x8 va[2], pb[4];
#pragma unroll
        for (int mi2 = 0; mi2 < 2; mi2++) {
            int row = mi2 * 16 + lr;
            va[mi2] = *(const f16x8*)(sm + 8192 + row * 128 +
                                      ((ks * 64 + kq * 16) ^ ((row & 7) << 4)));
        }
#pragma unroll
        for (int ni = 0; ni < 4; ni++) {
            int qq = ni * 16 + lr;
            pb[ni] = *(const f16x8*)(sm + qq * 128 +
                                     ((ks * 64 + kq * 16) ^ ((qq & 7) << 4)));
        }
#pragma unroll
        for (int mi2 = 0; mi2 < 2; mi2++)
#pragma unroll
            for (int ni = 0; ni < 4; ni++)
                oa[mi2][ni] = __builtin_amdgcn_mfma_f32_16x16x32_f16(va[mi2], pb[ni], oa[mi2][ni], 0, 0, 0);
    }

#pragma unroll
    for (int mi2 = 0; mi2 < 2; mi2++)
#pragma unroll
        for (int ni = 0; ni < 4; ni++) {
            f16 t4[4];
#pragma unroll
            for (int j = 0; j < 4; j++) t4[j] = (f16)(oa[mi2][ni][j] * inv[ni]);
            int qq = ni * 16 + lr;
            *(uint2*)(sm + 12288 + qq * 64 + ((mi2 * 32 + kq * 8) ^ ((qq & 3) << 4))) =
                *(const uint2*)t4;
        }
    __syncthreads();

    f16* dst = aw + ((size_t)(wl * 64 + lane)) * CC + h * 32;
#pragma unroll
    for (int c = 0; c < 4; c++) {
        uint4 wv = *(const uint4*)(sm + 12288 + lane * 64 +
                                   ((c * 16) ^ ((lane & 3) << 4)));
        *(uint4*)(dst + c * 8) = wv;
    }
}

extern "C" void kernel_launch(void* const* d_in, const int* in_sizes, int n_in,
                              void* d_out, int out_size, void* d_ws, size_t ws_size,
                              hipStream_t stream) {
    (void)in_sizes; (void)n_in; (void)out_size; (void)ws_size;
    const float* x      = (const float*)d_in[0];
    const float* g1     = (const float*)d_in[1];
    const float* b1     = (const float*)d_in[2];
    const float* qkv_w  = (const float*)d_in[3];
    const float* qkv_b  = (const float*)d_in[4];
    const float* rpb    = (const float*)d_in[5];
    const float* proj_w = (const float*)d_in[6];
    const float* proj_b = (const float*)d_in[7];
    const float* g2     = (const float*)d_in[8];
    const float* b2     = (const float*)d_in[9];
    const float* fc1_w  = (const float*)d_in[10];
    const float* fc1_b  = (const float*)d_in[11];
    const float* fc2_w  = (const float*)d_in[12];
    const float* fc2_b  = (const float*)d_in[13];
    float* out = (float*)d_out;
    char* ws = (char*)d_ws;
    f16* wq = (f16*)(ws + OFF_WQ);
    f16* wp = (f16*)(ws + OFF_WP);
    f16* w1 = (f16*)(ws + OFF_W1);
    f16* w2 = (f16*)(ws + OFF_W2);
    f16* awb = (f16*)(ws + OFF_R1);
    static constexpr size_t QSZ = (size_t)CWINS * 8 * 64 * 32 * 2; // 16,777,216 B
    f16* hwin = (f16*)(ws + OFF_R2);
    f16* qb   = (f16*)(ws + OFF_R2 + QSZ);
    f16* kb   = (f16*)(ws + OFF_R2 + 2 * QSZ);
    f16* vb   = (f16*)(ws + OFF_R2 + 3 * QSZ);
    f16* m_in = (f16*)(ws + OFF_R2);

    k_cvt<<<768, 256, 0, stream>>>(qkv_w, wq, 768 * 256);
    k_cvt<<<256, 256, 0, stream>>>(proj_w, wp, 256 * 256);
    k_cvt<<<1024, 256, 0, stream>>>(fc1_w, w1, 1024 * 256);
    k_cvt<<<1024, 256, 0, stream>>>(fc2_w, w2, 1024 * 256);

    // --- attention phase: per chunk LN1 -> QKV -> attn (writes full AW) ---
    for (int c = 0; c < ACH; c++) {
        k_ln<<<AROWS / 4, 256, 0, stream>>>(x, g1, b1, hwin, c * AROWS);
        k_qkv<<<dim3(AROWS / 128, 6), 256, 0, stream>>>(
            hwin, wq, qkv_b, qb, kb, vb);
        k_attn<<<CWINS * 8, 64, 0, stream>>>(
            qb, kb, vb, rpb, awb + (size_t)c * AROWS * CC, c * CWINS);
    }
    // proj over full M, fused un-shift + residual -> out, fused LN2 -> m_in
    k_proj<<<ROWS / 64, 256, 0, stream>>>(awb, wp, proj_b, x, out, m_in, g2, b2);

    // --- fused MLP (no mh round-trip), single launch over full M ---
    k_mlp2<<<ROWS / 64, 256, 0, stream>>>(m_in, w1, w2, fc1_b, fc2_b, out);
}

// Round 15
// 607.587 us; speedup vs baseline: 1.2102x; 1.0323x over previous
//
#include <hip/hip_runtime.h>
#include <hip/hip_bf16.h>
#include <stdint.h>

using f16 = _Float16;
typedef _Float16 f16x8 __attribute__((ext_vector_type(8)));
typedef float f32x4 __attribute__((ext_vector_type(4)));

static constexpr int HW = 4096;        // H*W
static constexpr int CC = 256;         // channels
static constexpr int ROWS = 131072;    // B*H*W
static constexpr int ACH = 4;          // attention-phase chunks
static constexpr int AROWS = ROWS / ACH;      // 32768 rows / chunk
static constexpr int CWINS = AROWS / 64;      // 512 windows / chunk
static constexpr int SSH = 4;          // shift

// workspace layout (bytes)
static constexpr size_t OFF_WQ = 0;                               // qkv_w f16  768*256
static constexpr size_t OFF_WP = OFF_WQ + (size_t)768*256*2;      // proj_w f16 256*256
static constexpr size_t OFF_W1 = OFF_WP + (size_t)256*256*2;      // fc1_w f16  1024*256
static constexpr size_t OFF_W2 = OFF_W1 + (size_t)1024*256*2;     // fc2_w f16  256*1024
static constexpr size_t OFF_R1 = OFF_W2 + (size_t)256*1024*2;     // 67,108,864 B region
static constexpr size_t OFF_R2 = OFF_R1 + (size_t)ROWS*CC*2;      // 67,108,864 B region
// R1: AW full (131072x256 f16). R2: hwin chunk + Q + K + V -> then m_in full.

__device__ __forceinline__ void gload16(void* lds, const void* g) {
    __builtin_amdgcn_global_load_lds(
        (const __attribute__((address_space(1))) unsigned int*)g,
        (__attribute__((address_space(3))) unsigned int*)lds, 16, 0, 0);
}

__global__ void k_cvt(const float* __restrict__ s, f16* __restrict__ d, int n) {
    int i = blockIdx.x * 256 + threadIdx.x;
    if (i < n) d[i] = (f16)s[i];
}

// LayerNorm over C=256, dest row (windowed+rolled) gathers from source row of x.
__global__ __launch_bounds__(256) void k_ln(const float* __restrict__ x,
                                            const float* __restrict__ g,
                                            const float* __restrict__ be,
                                            f16* __restrict__ dst, int rowbase) {
    int lrow = blockIdx.x * 4 + (threadIdx.x >> 6);
    int grow = rowbase + lrow;
    int lane = threadIdx.x & 63;
    int n = grow & 63, win = (grow >> 6) & 63, b = grow >> 12;
    int hh  = ((win >> 3) << 3) | (n >> 3);
    int wwc = ((win & 7) << 3) | (n & 7);
    int ho = (hh + SSH) & 63, wo = (wwc + SSH) & 63;
    size_t srow = (size_t)b * HW + ho * 64 + wo;
    float4 v = ((const float4*)(x + srow * CC))[lane];
    float s  = v.x + v.y + v.z + v.w;
    float s2 = v.x*v.x + v.y*v.y + v.z*v.z + v.w*v.w;
#pragma unroll
    for (int off = 32; off; off >>= 1) { s += __shfl_xor(s, off); s2 += __shfl_xor(s2, off); }
    float mean = s * (1.f/256.f);
    float rstd = rsqrtf(s2 * (1.f/256.f) - mean*mean + 1e-5f);
    float4 gv = ((const float4*)g)[lane];
    float4 bv = ((const float4*)be)[lane];
    f16 ob[4];
    ob[0] = (f16)((v.x-mean)*rstd*gv.x + bv.x);
    ob[1] = (f16)((v.y-mean)*rstd*gv.y + bv.y);
    ob[2] = (f16)((v.z-mean)*rstd*gv.z + bv.z);
    ob[3] = (f16)((v.w-mean)*rstd*gv.w + bv.w);
    *(uint2*)(dst + (size_t)lrow * CC + lane * 4) = *(const uint2*)ob;
}

// QKV GEMM: out = A * Wt^T (+bias), 128x128 tile, BK=32, 2-phase double-buffer.
__global__ __launch_bounds__(256) void k_qkv(const f16* __restrict__ A,
                                             const f16* __restrict__ Wt,
                                             const float* __restrict__ bias,
                                             f16* __restrict__ q, f16* __restrict__ kk,
                                             f16* __restrict__ vv) {
    __shared__ f16 As[2][128 * 32];
    __shared__ f16 Bs[2][128 * 32];
    const int tid = threadIdx.x;
    const int m0 = blockIdx.x * 128, n0 = blockIdx.y * 128;
    const int wave = tid >> 6, lane = tid & 63;
    const int wm = (wave >> 1) * 64, wn = (wave & 1) * 64;
    const int lr = lane & 15, kq = lane >> 4;
    const int i0 = wave * 128 + lane;
    const int r0 = i0 >> 2, c0 = (i0 & 3) * 8;
    const int i1 = i0 + 64;
    const int r1 = i1 >> 2, c1 = (i1 & 3) * 8;
    const int base0 = wave * 1024, base1 = base0 + 512;

    auto stage = [&](int b, int k0) {
        gload16(&As[b][base0], &A [(size_t)(m0 + r0) * CC + k0 + c0]);
        gload16(&Bs[b][base0], &Wt[(size_t)(n0 + r0) * CC + k0 + c0]);
        gload16(&As[b][base1], &A [(size_t)(m0 + r1) * CC + k0 + c1]);
        gload16(&Bs[b][base1], &Wt[(size_t)(n0 + r1) * CC + k0 + c1]);
    };

    f32x4 acc[4][4];
#pragma unroll
    for (int i = 0; i < 4; i++)
#pragma unroll
        for (int j = 0; j < 4; j++) acc[i][j] = f32x4{0.f, 0.f, 0.f, 0.f};

    stage(0, 0);
    __syncthreads();
    for (int s = 0; s < 8; s++) {
        int cur = s & 1;
        if (s + 1 < 8) stage(cur ^ 1, (s + 1) * 32);
        f16x8 af[4], bfv[4];
#pragma unroll
        for (int i = 0; i < 4; i++) {
            af[i]  = *(const f16x8*)(&As[cur][(wm + i * 16 + lr) * 32 + kq * 8]);
            bfv[i] = *(const f16x8*)(&Bs[cur][(wn + i * 16 + lr) * 32 + kq * 8]);
        }
#pragma unroll
        for (int mi = 0; mi < 4; mi++)
#pragma unroll
            for (int ni = 0; ni < 4; ni++)
                acc[mi][ni] = __builtin_amdgcn_mfma_f32_16x16x32_f16(af[mi], bfv[ni], acc[mi][ni], 0, 0, 0);
        __syncthreads();
    }

#pragma unroll
    for (int mi = 0; mi < 4; mi++)
#pragma unroll
        for (int ni = 0; ni < 4; ni++)
#pragma unroll
            for (int j = 0; j < 4; j++) {
                int lrow = m0 + wm + mi * 16 + kq * 4 + j;   // C/D: row=(lane>>4)*4+j
                int gcol = n0 + wn + ni * 16 + lr;           //      col=lane&15
                float val = acc[mi][ni][j] + bias[gcol];
                int s = gcol >> 8, h2 = (gcol >> 5) & 7, d = gcol & 31;
                if (s == 0) val *= 0.1767766952966369f;  // HD^-0.5
                f16* dst = (s == 0) ? q : (s == 1 ? kk : vv);
                int winl = lrow >> 6, n = lrow & 63;
                dst[(((size_t)winl * 8 + h2) * 64 + n) * 32 + d] = (f16)val;
            }
}

// proj GEMM, tile 64 rows x 256 cols (full row per block), 4 waves (1x4 of 64x64).
// Epilogue: + proj bias, + un-shift scatter + shortcut residual -> d_out (f32),
// then in-block LayerNorm2 over the complete 256-wide row -> m_in (f16).
__global__ __launch_bounds__(256, 2) void k_proj(const f16* __restrict__ A,
                                                 const f16* __restrict__ Wt,
                                                 const float* __restrict__ bias,
                                                 const float* __restrict__ x_in,
                                                 float* __restrict__ outf,
                                                 f16* __restrict__ m_out,
                                                 const float* __restrict__ g2,
                                                 const float* __restrict__ b2) {
    __shared__ f16 As[2][64 * 32];
    __shared__ f16 Bs[2][256 * 32];
    __shared__ float rsum[4][64];
    __shared__ float rsq[4][64];
    const int tid = threadIdx.x;
    const int m0 = blockIdx.x * 64;
    const int wave = tid >> 6, lane = tid & 63;
    const int lr = lane & 15, kq = lane >> 4;
    const int ar = tid >> 2, ac = (tid & 3) * 8;   // A stage: 256 chunks, 1/thread

    auto stage = [&](int b, int k0) {
        gload16(&As[b][wave * 512], &A[(size_t)(m0 + ar) * CC + k0 + ac]);
#pragma unroll
        for (int r = 0; r < 4; r++)
            gload16(&Bs[b][(r * 256 + wave * 64) * 8],
                    &Wt[(size_t)(r * 64 + ar) * CC + k0 + ac]);
    };

    f32x4 acc[4][4];
#pragma unroll
    for (int i = 0; i < 4; i++)
#pragma unroll
        for (int j = 0; j < 4; j++) acc[i][j] = f32x4{0.f, 0.f, 0.f, 0.f};

    stage(0, 0);
    __syncthreads();
    for (int s = 0; s < 8; s++) {
        int cur = s & 1;
        if (s + 1 < 8) stage(cur ^ 1, (s + 1) * 32);
        f16x8 af[4], bfv[4];
#pragma unroll
        for (int i = 0; i < 4; i++) {
            af[i]  = *(const f16x8*)(&As[cur][(i * 16 + lr) * 32 + kq * 8]);
            bfv[i] = *(const f16x8*)(&Bs[cur][(wave * 64 + i * 16 + lr) * 32 + kq * 8]);
        }
#pragma unroll
        for (int mi = 0; mi < 4; mi++)
#pragma unroll
            for (int ni = 0; ni < 4; ni++)
                acc[mi][ni] = __builtin_amdgcn_mfma_f32_16x16x32_f16(af[mi], bfv[ni], acc[mi][ni], 0, 0, 0);
        __syncthreads();
    }

    // ---- epilogue: x2 = proj + bias + shortcut (per un-shift scatter) ----
    int srows[4][4];
#pragma unroll
    for (int mi = 0; mi < 4; mi++)
#pragma unroll
        for (int j = 0; j < 4; j++) {
            int row = m0 + mi * 16 + kq * 4 + j;       // windowed-order global row
            int n = row & 63, win = (row >> 6) & 63, b = row >> 12;
            int hh  = ((win >> 3) << 3) | (n >> 3);
            int wwc = ((win & 7) << 3) | (n & 7);
            int ho = (hh + SSH) & 63, wo = (wwc + SSH) & 63;
            srows[mi][j] = b * HW + ho * 64 + wo;
        }
    float bv[4], gv[4], b2v[4];
#pragma unroll
    for (int ni = 0; ni < 4; ni++) {
        int gcol = wave * 64 + ni * 16 + lr;
        bv[ni] = bias[gcol]; gv[ni] = g2[gcol]; b2v[ni] = b2[gcol];
    }
    float ps[4][4], qs[4][4];
#pragma unroll
    for (int mi = 0; mi < 4; mi++)
#pragma unroll
        for (int j = 0; j < 4; j++) { ps[mi][j] = 0.f; qs[mi][j] = 0.f; }
#pragma unroll
    for (int mi = 0; mi < 4; mi++)
#pragma unroll
        for (int ni = 0; ni < 4; ni++) {
            int gcol = wave * 64 + ni * 16 + lr;
#pragma unroll
            for (int j = 0; j < 4; j++) {
                size_t idx = (size_t)srows[mi][j] * CC + gcol;
                float v = acc[mi][ni][j] + bv[ni] + x_in[idx];
                acc[mi][ni][j] = v;
                outf[idx] = v;
                ps[mi][j] += v; qs[mi][j] += v * v;
            }
        }
#pragma unroll
    for (int off = 1; off < 16; off <<= 1)
#pragma unroll
        for (int mi = 0; mi < 4; mi++)
#pragma unroll
            for (int j = 0; j < 4; j++) {
                ps[mi][j] += __shfl_xor(ps[mi][j], off);
                qs[mi][j] += __shfl_xor(qs[mi][j], off);
            }
    if (lr == 0) {
#pragma unroll
        for (int mi = 0; mi < 4; mi++)
#pragma unroll
            for (int j = 0; j < 4; j++) {
                int rl = mi * 16 + kq * 4 + j;
                rsum[wave][rl] = ps[mi][j];
                rsq[wave][rl]  = qs[mi][j];
            }
    }
    __syncthreads();
    float mean_a[4][4], rstd_a[4][4];
#pragma unroll
    for (int mi = 0; mi < 4; mi++)
#pragma unroll
        for (int j = 0; j < 4; j++) {
            int rl = mi * 16 + kq * 4 + j;
            float s  = rsum[0][rl] + rsum[1][rl] + rsum[2][rl] + rsum[3][rl];
            float s2 = rsq[0][rl] + rsq[1][rl] + rsq[2][rl] + rsq[3][rl];
            float mean = s * (1.f/256.f);
            float var  = s2 * (1.f/256.f) - mean * mean;
            mean_a[mi][j] = mean;
            rstd_a[mi][j] = rsqrtf(var + 1e-5f);
        }
#pragma unroll
    for (int mi = 0; mi < 4; mi++)
#pragma unroll
        for (int ni = 0; ni < 4; ni++) {
            int gcol = wave * 64 + ni * 16 + lr;
#pragma unroll
            for (int j = 0; j < 4; j++) {
                float m = (acc[mi][ni][j] - mean_a[mi][j]) * rstd_a[mi][j] * gv[ni] + b2v[ni];
                m_out[(size_t)srows[mi][j] * CC + gcol] = (f16)m;
            }
        }
}

// Fused MLP: out += fc2(gelu(fc1(m_in))); NO mh round-trip.
// fc1 operand-SWAPPED (A := w1, B := x) so the j-dim walks consecutive hid ->
// gelu'd h written as aligned uint2 into swizzled h[q][hid].
// Tanh-GELU in R10's exact expression shape; ONLY the precise f32 division is
// replaced with v_rcp_f32 (2.f/x -> 2.f*rcp(x)): one-variable isolation of
// R12's VALU saving without its expression rewrite (which cost +32 VGPR).
// fc2: h swizzled b128 reads, acc2 persistent across nb (K-loop accumulator).
__global__ __launch_bounds__(256) void k_mlp2(const f16* __restrict__ A,
                                              const f16* __restrict__ w1,
                                              const f16* __restrict__ w2,
                                              const float* __restrict__ fb1,
                                              const float* __restrict__ fb2,
                                              float* __restrict__ out) {
    __shared__ char sm[49152];
    char* hbuf = sm;                 // [64][128] f16, row stride 256B, XOR-swizzled
    char* S    = sm + 16384;         // 32KB: fc1 staging (As 8K + Bs1 16K) / fc2 Bs2 32K
    f16* As  = (f16*)S;              // [2][64*32]
    f16* Bs1 = (f16*)(S + 8192);     // [2][128*32]
    f16* Bs2 = (f16*)S;              // [2][256*32]
    const int tid = threadIdx.x, wave = tid >> 6, lane = tid & 63;
    const int lr = lane & 15, kq = lane >> 4;
    const int m0 = blockIdx.x * 64;
    const int ar = tid >> 2, ac = (tid & 3) * 8;

    f32x4 acc2[4][4];
#pragma unroll
    for (int i = 0; i < 4; i++)
#pragma unroll
        for (int j = 0; j < 4; j++) acc2[i][j] = f32x4{0.f, 0.f, 0.f, 0.f};

    for (int nb = 0; nb < 8; nb++) {
        auto stage1 = [&](int b, int k0) {
            gload16(&As[b * 2048 + wave * 512], &A[(size_t)(m0 + ar) * CC + k0 + ac]);
            gload16(&Bs1[b * 4096 + wave * 512],
                    &w1[(size_t)(nb * 128 + ar) * CC + k0 + ac]);
            gload16(&Bs1[b * 4096 + 2048 + wave * 512],
                    &w1[(size_t)(nb * 128 + 64 + ar) * CC + k0 + ac]);
        };
        // ---- fc1 slice (swapped): acc1[hid frags][q frags] ----
        f32x4 acc1[2][4];
#pragma unroll
        for (int i = 0; i < 2; i++)
#pragma unroll
            for (int j = 0; j < 4; j++) acc1[i][j] = f32x4{0.f, 0.f, 0.f, 0.f};
        stage1(0, 0);
        __syncthreads();
#pragma unroll
        for (int ks = 0; ks < 8; ks++) {
            int cur = ks & 1;
            if (ks + 1 < 8) stage1(cur ^ 1, (ks + 1) * 32);
            f16x8 aw1[2], bx[4];
#pragma unroll
            for (int hi = 0; hi < 2; hi++)
                aw1[hi] = *(const f16x8*)(&Bs1[cur * 4096 +
                                               (wave * 32 + hi * 16 + lr) * 32 + kq * 8]);
#pragma unroll
            for (int qi = 0; qi < 4; qi++)
                bx[qi] = *(const f16x8*)(&As[cur * 2048 + (qi * 16 + lr) * 32 + kq * 8]);
#pragma unroll
            for (int hi = 0; hi < 2; hi++)
#pragma unroll
                for (int qi = 0; qi < 4; qi++)
                    acc1[hi][qi] = __builtin_amdgcn_mfma_f32_16x16x32_f16(
                        aw1[hi], bx[qi], acc1[hi][qi], 0, 0, 0);
            __syncthreads();
        }
        // ---- gelu -> h (vectorized uint2, swizzled), stage fc2 B after ----
#pragma unroll
        for (int hi = 0; hi < 2; hi++) {
            float4 bb4 = *(const float4*)&fb1[nb * 128 + wave * 32 + hi * 16 + kq * 4];
            const float bb[4] = {bb4.x, bb4.y, bb4.z, bb4.w};
            const int hidb = wave * 64 + hi * 32 + kq * 8;   // byte = 2*hid base
#pragma unroll
            for (int qi = 0; qi < 4; qi++) {
                f16 t4[4];
#pragma unroll
                for (int j = 0; j < 4; j++) {
                    float v = acc1[hi][qi][j] + bb[j];
                    float z = 0.7978845608028654f * (v + 0.044715f * v * v * v);
                    float t = 1.f - 2.f * __builtin_amdgcn_rcpf(__expf(2.f * z) + 1.f);
                    t4[j] = (f16)(0.5f * v * (1.f + t));
                }
                int qrow = qi * 16 + lr;
                *(uint2*)(hbuf + qrow * 256 + (hidb ^ ((qrow & 7) << 4))) =
                    *(const uint2*)t4;
            }
        }
        auto stage2 = [&](int b, int k0) {
#pragma unroll
            for (int t = 0; t < 4; t++)
                gload16(&Bs2[b * 8192 + t * 2048 + wave * 512],
                        &w2[(size_t)(t * 64 + ar) * 1024 + nb * 128 + k0 + ac]);
        };
        stage2(0, 0);
        __syncthreads();     // h visible + Bs2[0] landed (barrier drains vmcnt)
        // ---- fc2 partial: acc2[64 q rows][wave's 64 out cols] += h @ w2_nb^T ----
#pragma unroll
        for (int ks = 0; ks < 4; ks++) {
            int cur = ks & 1;
            if (ks + 1 < 4) stage2(cur ^ 1, (ks + 1) * 32);
            f16x8 ah[4], bw[4];
#pragma unroll
            for (int mi = 0; mi < 4; mi++) {
                int row = mi * 16 + lr;
                ah[mi] = *(const f16x8*)(hbuf + row * 256 +
                                         ((ks * 64 + kq * 16) ^ ((row & 7) << 4)));
            }
#pragma unroll
            for (int ni = 0; ni < 4; ni++)
                bw[ni] = *(const f16x8*)(&Bs2[cur * 8192 +
                                              (wave * 64 + ni * 16 + lr) * 32 + kq * 8]);
#pragma unroll
            for (int mi = 0; mi < 4; mi++)
#pragma unroll
                for (int ni = 0; ni < 4; ni++)
                    acc2[mi][ni] = __builtin_amdgcn_mfma_f32_16x16x32_f16(
                        ah[mi], bw[ni], acc2[mi][ni], 0, 0, 0);
            __syncthreads();
        }
    }

    // ---- epilogue: out += acc2 + fb2 (coalesced 64B f32 segments) ----
#pragma unroll
    for (int mi = 0; mi < 4; mi++)
#pragma unroll
        for (int ni = 0; ni < 4; ni++)
#pragma unroll
            for (int j = 0; j < 4; j++) {
                int qrow = m0 + mi * 16 + kq * 4 + j;
                int oc = wave * 64 + ni * 16 + lr;
                size_t idx = (size_t)qrow * CC + oc;
                out[idx] = out[idx] + acc2[mi][ni][j] + fb2[oc];
            }
}

// MFMA attention: one wave per (window, head). S^T = mfma(K,Q); in-register
// softmax over keys; j-packed b64 swizzled LDS P-transpose; O^T = mfma(V^T, P);
// swizzled O-transpose -> 4 coalesced stores. 17.3KB LDS.
__global__ __launch_bounds__(64) void k_attn(const f16* __restrict__ q,
                                             const f16* __restrict__ kk,
                                             const f16* __restrict__ vv,
                                             const float* __restrict__ rpb,
                                             f16* __restrict__ aw, int winbase) {
    __shared__ char sm[17408];      // P[64][64] 8KB | VT[32][64] 4KB | O[64][32] 4KB | rl 900B
    float* rl = (float*)(sm + 16384);
    const int wl = blockIdx.x >> 3, h = blockIdx.x & 7;
    const int lane = threadIdx.x;
    const int lr = lane & 15, kq = lane >> 4;
    const size_t base = ((size_t)wl * 8 + h) * 2048;

    for (int i = lane; i < 225; i += 64) rl[i] = rpb[i * 8 + h];

    {
        f16 vr[32];
        const uint4* vs = (const uint4*)(vv + base + lane * 32);
#pragma unroll
        for (int c = 0; c < 4; c++) *(uint4*)&vr[c * 8] = vs[c];
#pragma unroll
        for (int d = 0; d < 32; d++)
            *(f16*)(sm + 8192 + d * 128 + ((lane * 2) ^ ((d & 7) << 4))) = vr[d];
    }

    f16x8 kf[4], qf[4];
#pragma unroll
    for (int t = 0; t < 4; t++) {
        kf[t] = *(const f16x8*)(kk + base + (size_t)(t * 16 + lr) * 32 + kq * 8);
        qf[t] = *(const f16x8*)(q  + base + (size_t)(t * 16 + lr) * 32 + kq * 8);
    }

    f32x4 st[4][4];
#pragma unroll
    for (int mi = 0; mi < 4; mi++)
#pragma unroll
        for (int ni = 0; ni < 4; ni++) st[mi][ni] = f32x4{0.f, 0.f, 0.f, 0.f};
#pragma unroll
    for (int mi = 0; mi < 4; mi++)
#pragma unroll
        for (int ni = 0; ni < 4; ni++)
            st[mi][ni] = __builtin_amdgcn_mfma_f32_16x16x32_f16(kf[mi], qf[ni], st[mi][ni], 0, 0, 0);

    __syncthreads();

    const int gwin = (winbase + wl) & 63;
    const int wh = gwin >> 3, ww = gwin & 7;
    int yq[4], xq[4], rq[4];
#pragma unroll
    for (int ni = 0; ni < 4; ni++) {
        int qq = ni * 16 + lr;
        yq[ni] = qq >> 3; xq[ni] = qq & 7;
        rq[ni] = ((wh < 7) ? 0 : ((yq[ni] < 4) ? 1 : 2)) * 3 +
                 ((ww < 7) ? 0 : ((xq[ni] < 4) ? 1 : 2));
    }
#pragma unroll
    for (int mi = 0; mi < 4; mi++)
#pragma unroll
        for (int j = 0; j < 4; j++) {
            int kt = mi * 16 + kq * 4 + j;
            int yk = kt >> 3, xk = kt & 7;
            int rk = ((wh < 7) ? 0 : ((yk < 4) ? 1 : 2)) * 3 +
                     ((ww < 7) ? 0 : ((xk < 4) ? 1 : 2));
#pragma unroll
            for (int ni = 0; ni < 4; ni++) {
                float b = rl[(yq[ni] - yk + 7) * 15 + (xq[ni] - xk + 7)];
                if (rq[ni] != rk) b -= 100.f;
                st[mi][ni][j] += b;
            }
        }

    float mx[4] = {-1e30f, -1e30f, -1e30f, -1e30f};
#pragma unroll
    for (int mi = 0; mi < 4; mi++)
#pragma unroll
        for (int ni = 0; ni < 4; ni++)
#pragma unroll
            for (int j = 0; j < 4; j++) mx[ni] = fmaxf(mx[ni], st[mi][ni][j]);
#pragma unroll
    for (int ni = 0; ni < 4; ni++) {
        mx[ni] = fmaxf(mx[ni], __shfl_xor(mx[ni], 16));
        mx[ni] = fmaxf(mx[ni], __shfl_xor(mx[ni], 32));
    }
    float sme[4] = {0.f, 0.f, 0.f, 0.f};
#pragma unroll
    for (int mi = 0; mi < 4; mi++)
#pragma unroll
        for (int ni = 0; ni < 4; ni++)
#pragma unroll
            for (int j = 0; j < 4; j++) {
                float e = __expf(st[mi][ni][j] - mx[ni]);
                st[mi][ni][j] = e;
                sme[ni] += e;
            }
#pragma unroll
    for (int ni = 0; ni < 4; ni++) {
        sme[ni] += __shfl_xor(sme[ni], 16);
        sme[ni] += __shfl_xor(sme[ni], 32);
    }
    float inv[4];
#pragma unroll
    for (int ni = 0; ni < 4; ni++) inv[ni] = 1.f / sme[ni];

#pragma unroll
    for (int mi = 0; mi < 4; mi++)
#pragma unroll
        for (int ni = 0; ni < 4; ni++) {
            f16 t4[4];
#pragma unroll
            for (int j = 0; j < 4; j++) t4[j] = (f16)st[mi][ni][j];
            int qq = ni * 16 + lr;
            *(uint2*)(sm + qq * 128 + ((mi * 32 + kq * 8) ^ ((qq & 7) << 4))) =
                *(const uint2*)t4;
        }
    __syncthreads();

    f32x4 oa[2][4];
#pragma unroll
    for (int mi2 = 0; mi2 < 2; mi2++)
#pragma unroll
        for (int ni = 0; ni < 4; ni++) oa[mi2][ni] = f32x4{0.f, 0.f, 0.f, 0.f};
#pragma unroll
    for (int ks = 0; ks < 2; ks++) {
        f16x8 va[2], pb[4];
#pragma unroll
        for (int mi2 = 0; mi2 < 2; mi2++) {
            int row = mi2 * 16 + lr;
            va[mi2] = *(const f16x8*)(sm + 8192 + row * 128 +
                                      ((ks * 64 + kq * 16) ^ ((row & 7) << 4)));
        }
#pragma unroll
        for (int ni = 0; ni < 4; ni++) {
            int qq = ni * 16 + lr;
            pb[ni] = *(const f16x8*)(sm + qq * 128 +
                                     ((ks * 64 + kq * 16) ^ ((qq & 7) << 4)));
        }
#pragma unroll
        for (int mi2 = 0; mi2 < 2; mi2++)
#pragma unroll
            for (int ni = 0; ni < 4; ni++)
                oa[mi2][ni] = __builtin_amdgcn_mfma_f32_16x16x32_f16(va[mi2], pb[ni], oa[mi2][ni], 0, 0, 0);
    }

#pragma unroll
    for (int mi2 = 0; mi2 < 2; mi2++)
#pragma unroll
        for (int ni = 0; ni < 4; ni++) {
            f16 t4[4];
#pragma unroll
            for (int j = 0; j < 4; j++) t4[j] = (f16)(oa[mi2][ni][j] * inv[ni]);
            int qq = ni * 16 + lr;
            *(uint2*)(sm + 12288 + qq * 64 + ((mi2 * 32 + kq * 8) ^ ((qq & 3) << 4))) =
                *(const uint2*)t4;
        }
    __syncthreads();

    f16* dst = aw + ((size_t)(wl * 64 + lane)) * CC + h * 32;
#pragma unroll
    for (int c = 0; c < 4; c++) {
        uint4 wv = *(const uint4*)(sm + 12288 + lane * 64 +
                                   ((c * 16) ^ ((lane & 3) << 4)));
        *(uint4*)(dst + c * 8) = wv;
    }
}

extern "C" void kernel_launch(void* const* d_in, const int* in_sizes, int n_in,
                              void* d_out, int out_size, void* d_ws, size_t ws_size,
                              hipStream_t stream) {
    (void)in_sizes; (void)n_in; (void)out_size; (void)ws_size;
    const float* x      = (const float*)d_in[0];
    const float* g1     = (const float*)d_in[1];
    const float* b1     = (const float*)d_in[2];
    const float* qkv_w  = (const float*)d_in[3];
    const float* qkv_b  = (const float*)d_in[4];
    const float* rpb    = (const float*)d_in[5];
    const float* proj_w = (const float*)d_in[6];
    const float* proj_b = (const float*)d_in[7];
    const float* g2     = (const float*)d_in[8];
    const float* b2     = (const float*)d_in[9];
    const float* fc1_w  = (const float*)d_in[10];
    const float* fc1_b  = (const float*)d_in[11];
    const float* fc2_w  = (const float*)d_in[12];
    const float* fc2_b  = (const float*)d_in[13];
    float* out = (float*)d_out;
    char* ws = (char*)d_ws;
    f16* wq = (f16*)(ws + OFF_WQ);
    f16* wp = (f16*)(ws + OFF_WP);
    f16* w1 = (f16*)(ws + OFF_W1);
    f16* w2 = (f16*)(ws + OFF_W2);
    f16* awb = (f16*)(ws + OFF_R1);
    static constexpr size_t QSZ = (size_t)CWINS * 8 * 64 * 32 * 2; // 16,777,216 B
    f16* hwin = (f16*)(ws + OFF_R2);
    f16* qb   = (f16*)(ws + OFF_R2 + QSZ);
    f16* kb   = (f16*)(ws + OFF_R2 + 2 * QSZ);
    f16* vb   = (f16*)(ws + OFF_R2 + 3 * QSZ);
    f16* m_in = (f16*)(ws + OFF_R2);

    k_cvt<<<768, 256, 0, stream>>>(qkv_w, wq, 768 * 256);
    k_cvt<<<256, 256, 0, stream>>>(proj_w, wp, 256 * 256);
    k_cvt<<<1024, 256, 0, stream>>>(fc1_w, w1, 1024 * 256);
    k_cvt<<<1024, 256, 0, stream>>>(fc2_w, w2, 1024 * 256);

    // --- attention phase: per chunk LN1 -> QKV -> attn (writes full AW) ---
    for (int c = 0; c < ACH; c++) {
        k_ln<<<AROWS / 4, 256, 0, stream>>>(x, g1, b1, hwin, c * AROWS);
        k_qkv<<<dim3(AROWS / 128, 6), 256, 0, stream>>>(
            hwin, wq, qkv_b, qb, kb, vb);
        k_attn<<<CWINS * 8, 64, 0, stream>>>(
            qb, kb, vb, rpb, awb + (size_t)c * AROWS * CC, c * CWINS);
    }
    // proj over full M, fused un-shift + residual -> out, fused LN2 -> m_in
    k_proj<<<ROWS / 64, 256, 0, stream>>>(awb, wp, proj_b, x, out, m_in, g2, b2);

    // --- fused MLP (no mh round-trip), single launch over full M ---
    k_mlp2<<<ROWS / 64, 256, 0, stream>>>(m_in, w1, w2, fc1_b, fc2_b, out);
}

// Round 16
// 605.083 us; speedup vs baseline: 1.2152x; 1.0041x over previous
//
#include <hip/hip_runtime.h>
#include <hip/hip_bf16.h>
#include <stdint.h>

using f16 = _Float16;
typedef _Float16 f16x8 __attribute__((ext_vector_type(8)));
typedef float f32x4 __attribute__((ext_vector_type(4)));

static constexpr int HW = 4096;        // H*W
static constexpr int CC = 256;         // channels
static constexpr int ROWS = 131072;    // B*H*W
static constexpr int ACH = 4;          // attention-phase chunks
static constexpr int AROWS = ROWS / ACH;      // 32768 rows / chunk
static constexpr int CWINS = AROWS / 64;      // 512 windows / chunk
static constexpr int SSH = 4;          // shift

// workspace layout (bytes)
static constexpr size_t OFF_WQ = 0;                               // qkv_w f16  768*256
static constexpr size_t OFF_WP = OFF_WQ + (size_t)768*256*2;      // proj_w f16 256*256
static constexpr size_t OFF_W1 = OFF_WP + (size_t)256*256*2;      // fc1_w f16  1024*256
static constexpr size_t OFF_W2 = OFF_W1 + (size_t)1024*256*2;     // fc2_w f16  256*1024
static constexpr size_t OFF_R1 = OFF_W2 + (size_t)256*1024*2;     // 67,108,864 B region
static constexpr size_t OFF_R2 = OFF_R1 + (size_t)ROWS*CC*2;      // 67,108,864 B region
// R1: AW full (131072x256 f16). R2: hwin chunk + Q + K + V -> then m_in full.
//
// LDS bank-swizzle (this round): every GEMM K-tile is [rows][32] f16 row-major
// in LDS; the 4 16B slots of each 64B row are PERMUTED by slot^=((row>>1)&3),
// applied on the GLOBAL source address (stays within the same 64B segment ->
// coalescing unchanged; LDS dest stays linear per global_load_lds rules).
// Fragment reads use the inverse XOR: slot = kq ^ ((lr>>1)&3).

__device__ __forceinline__ void gload16(void* lds, const void* g) {
    __builtin_amdgcn_global_load_lds(
        (const __attribute__((address_space(1))) unsigned int*)g,
        (__attribute__((address_space(3))) unsigned int*)lds, 16, 0, 0);
}

__global__ void k_cvt(const float* __restrict__ s, f16* __restrict__ d, int n) {
    int i = blockIdx.x * 256 + threadIdx.x;
    if (i < n) d[i] = (f16)s[i];
}

// LayerNorm over C=256, dest row (windowed+rolled) gathers from source row of x.
__global__ __launch_bounds__(256) void k_ln(const float* __restrict__ x,
                                            const float* __restrict__ g,
                                            const float* __restrict__ be,
                                            f16* __restrict__ dst, int rowbase) {
    int lrow = blockIdx.x * 4 + (threadIdx.x >> 6);
    int grow = rowbase + lrow;
    int lane = threadIdx.x & 63;
    int n = grow & 63, win = (grow >> 6) & 63, b = grow >> 12;
    int hh  = ((win >> 3) << 3) | (n >> 3);
    int wwc = ((win & 7) << 3) | (n & 7);
    int ho = (hh + SSH) & 63, wo = (wwc + SSH) & 63;
    size_t srow = (size_t)b * HW + ho * 64 + wo;
    float4 v = ((const float4*)(x + srow * CC))[lane];
    float s  = v.x + v.y + v.z + v.w;
    float s2 = v.x*v.x + v.y*v.y + v.z*v.z + v.w*v.w;
#pragma unroll
    for (int off = 32; off; off >>= 1) { s += __shfl_xor(s, off); s2 += __shfl_xor(s2, off); }
    float mean = s * (1.f/256.f);
    float rstd = rsqrtf(s2 * (1.f/256.f) - mean*mean + 1e-5f);
    float4 gv = ((const float4*)g)[lane];
    float4 bv = ((const float4*)be)[lane];
    f16 ob[4];
    ob[0] = (f16)((v.x-mean)*rstd*gv.x + bv.x);
    ob[1] = (f16)((v.y-mean)*rstd*gv.y + bv.y);
    ob[2] = (f16)((v.z-mean)*rstd*gv.z + bv.z);
    ob[3] = (f16)((v.w-mean)*rstd*gv.w + bv.w);
    *(uint2*)(dst + (size_t)lrow * CC + lane * 4) = *(const uint2*)ob;
}

// QKV GEMM: out = A * Wt^T (+bias), 128x128 tile, BK=32, 2-phase double-buffer.
// Bank-swizzled staging/reads (see header comment).
__global__ __launch_bounds__(256) void k_qkv(const f16* __restrict__ A,
                                             const f16* __restrict__ Wt,
                                             const float* __restrict__ bias,
                                             f16* __restrict__ q, f16* __restrict__ kk,
                                             f16* __restrict__ vv) {
    __shared__ f16 As[2][128 * 32];
    __shared__ f16 Bs[2][128 * 32];
    const int tid = threadIdx.x;
    const int m0 = blockIdx.x * 128, n0 = blockIdx.y * 128;
    const int wave = tid >> 6, lane = tid & 63;
    const int wm = (wave >> 1) * 64, wn = (wave & 1) * 64;
    const int lr = lane & 15, kq = lane >> 4;
    const int i0 = wave * 128 + lane;
    const int r0 = i0 >> 2, c0 = (((i0 & 3) ^ ((i0 >> 3) & 3))) * 8;  // swizzled slot
    const int i1 = i0 + 64;
    const int r1 = i1 >> 2, c1 = (((i1 & 3) ^ ((i1 >> 3) & 3))) * 8;
    const int base0 = wave * 1024, base1 = base0 + 512;
    const int ksw = (kq ^ ((lr >> 1) & 3)) * 8;                        // read slot

    auto stage = [&](int b, int k0) {
        gload16(&As[b][base0], &A [(size_t)(m0 + r0) * CC + k0 + c0]);
        gload16(&Bs[b][base0], &Wt[(size_t)(n0 + r0) * CC + k0 + c0]);
        gload16(&As[b][base1], &A [(size_t)(m0 + r1) * CC + k0 + c1]);
        gload16(&Bs[b][base1], &Wt[(size_t)(n0 + r1) * CC + k0 + c1]);
    };

    f32x4 acc[4][4];
#pragma unroll
    for (int i = 0; i < 4; i++)
#pragma unroll
        for (int j = 0; j < 4; j++) acc[i][j] = f32x4{0.f, 0.f, 0.f, 0.f};

    stage(0, 0);
    __syncthreads();
    for (int s = 0; s < 8; s++) {
        int cur = s & 1;
        if (s + 1 < 8) stage(cur ^ 1, (s + 1) * 32);
        f16x8 af[4], bfv[4];
#pragma unroll
        for (int i = 0; i < 4; i++) {
            af[i]  = *(const f16x8*)(&As[cur][(wm + i * 16 + lr) * 32 + ksw]);
            bfv[i] = *(const f16x8*)(&Bs[cur][(wn + i * 16 + lr) * 32 + ksw]);
        }
#pragma unroll
        for (int mi = 0; mi < 4; mi++)
#pragma unroll
            for (int ni = 0; ni < 4; ni++)
                acc[mi][ni] = __builtin_amdgcn_mfma_f32_16x16x32_f16(af[mi], bfv[ni], acc[mi][ni], 0, 0, 0);
        __syncthreads();
    }

#pragma unroll
    for (int mi = 0; mi < 4; mi++)
#pragma unroll
        for (int ni = 0; ni < 4; ni++)
#pragma unroll
            for (int j = 0; j < 4; j++) {
                int lrow = m0 + wm + mi * 16 + kq * 4 + j;   // C/D: row=(lane>>4)*4+j
                int gcol = n0 + wn + ni * 16 + lr;           //      col=lane&15
                float val = acc[mi][ni][j] + bias[gcol];
                int s = gcol >> 8, h2 = (gcol >> 5) & 7, d = gcol & 31;
                if (s == 0) val *= 0.1767766952966369f;  // HD^-0.5
                f16* dst = (s == 0) ? q : (s == 1 ? kk : vv);
                int winl = lrow >> 6, n = lrow & 63;
                dst[(((size_t)winl * 8 + h2) * 64 + n) * 32 + d] = (f16)val;
            }
}

// proj GEMM, tile 64 rows x 256 cols (full row per block), 4 waves (1x4 of 64x64).
// Bank-swizzled staging/reads. Epilogue: + bias, un-shift scatter + residual
// -> d_out (f32), then in-block LayerNorm2 over the 256-wide row -> m_in (f16).
__global__ __launch_bounds__(256, 2) void k_proj(const f16* __restrict__ A,
                                                 const f16* __restrict__ Wt,
                                                 const float* __restrict__ bias,
                                                 const float* __restrict__ x_in,
                                                 float* __restrict__ outf,
                                                 f16* __restrict__ m_out,
                                                 const float* __restrict__ g2,
                                                 const float* __restrict__ b2) {
    __shared__ f16 As[2][64 * 32];
    __shared__ f16 Bs[2][256 * 32];
    __shared__ float rsum[4][64];
    __shared__ float rsq[4][64];
    const int tid = threadIdx.x;
    const int m0 = blockIdx.x * 64;
    const int wave = tid >> 6, lane = tid & 63;
    const int lr = lane & 15, kq = lane >> 4;
    const int ar = tid >> 2;
    const int ac = (((tid & 3) ^ ((tid >> 3) & 3))) * 8;   // swizzled source slot
    const int ksw = (kq ^ ((lr >> 1) & 3)) * 8;            // read slot

    auto stage = [&](int b, int k0) {
        gload16(&As[b][wave * 512], &A[(size_t)(m0 + ar) * CC + k0 + ac]);
#pragma unroll
        for (int r = 0; r < 4; r++)
            gload16(&Bs[b][(r * 256 + wave * 64) * 8],
                    &Wt[(size_t)(r * 64 + ar) * CC + k0 + ac]);
    };

    f32x4 acc[4][4];
#pragma unroll
    for (int i = 0; i < 4; i++)
#pragma unroll
        for (int j = 0; j < 4; j++) acc[i][j] = f32x4{0.f, 0.f, 0.f, 0.f};

    stage(0, 0);
    __syncthreads();
    for (int s = 0; s < 8; s++) {
        int cur = s & 1;
        if (s + 1 < 8) stage(cur ^ 1, (s + 1) * 32);
        f16x8 af[4], bfv[4];
#pragma unroll
        for (int i = 0; i < 4; i++) {
            af[i]  = *(const f16x8*)(&As[cur][(i * 16 + lr) * 32 + ksw]);
            bfv[i] = *(const f16x8*)(&Bs[cur][(wave * 64 + i * 16 + lr) * 32 + ksw]);
        }
#pragma unroll
        for (int mi = 0; mi < 4; mi++)
#pragma unroll
            for (int ni = 0; ni < 4; ni++)
                acc[mi][ni] = __builtin_amdgcn_mfma_f32_16x16x32_f16(af[mi], bfv[ni], acc[mi][ni], 0, 0, 0);
        __syncthreads();
    }

    // ---- epilogue: x2 = proj + bias + shortcut (per un-shift scatter) ----
    int srows[4][4];
#pragma unroll
    for (int mi = 0; mi < 4; mi++)
#pragma unroll
        for (int j = 0; j < 4; j++) {
            int row = m0 + mi * 16 + kq * 4 + j;       // windowed-order global row
            int n = row & 63, win = (row >> 6) & 63, b = row >> 12;
            int hh  = ((win >> 3) << 3) | (n >> 3);
            int wwc = ((win & 7) << 3) | (n & 7);
            int ho = (hh + SSH) & 63, wo = (wwc + SSH) & 63;
            srows[mi][j] = b * HW + ho * 64 + wo;
        }
    float bv[4], gv[4], b2v[4];
#pragma unroll
    for (int ni = 0; ni < 4; ni++) {
        int gcol = wave * 64 + ni * 16 + lr;
        bv[ni] = bias[gcol]; gv[ni] = g2[gcol]; b2v[ni] = b2[gcol];
    }
    float ps[4][4], qs[4][4];
#pragma unroll
    for (int mi = 0; mi < 4; mi++)
#pragma unroll
        for (int j = 0; j < 4; j++) { ps[mi][j] = 0.f; qs[mi][j] = 0.f; }
#pragma unroll
    for (int mi = 0; mi < 4; mi++)
#pragma unroll
        for (int ni = 0; ni < 4; ni++) {
            int gcol = wave * 64 + ni * 16 + lr;
#pragma unroll
            for (int j = 0; j < 4; j++) {
                size_t idx = (size_t)srows[mi][j] * CC + gcol;
                float v = acc[mi][ni][j] + bv[ni] + x_in[idx];
                acc[mi][ni][j] = v;
                outf[idx] = v;
                ps[mi][j] += v; qs[mi][j] += v * v;
            }
        }
#pragma unroll
    for (int off = 1; off < 16; off <<= 1)
#pragma unroll
        for (int mi = 0; mi < 4; mi++)
#pragma unroll
            for (int j = 0; j < 4; j++) {
                ps[mi][j] += __shfl_xor(ps[mi][j], off);
                qs[mi][j] += __shfl_xor(qs[mi][j], off);
            }
    if (lr == 0) {
#pragma unroll
        for (int mi = 0; mi < 4; mi++)
#pragma unroll
            for (int j = 0; j < 4; j++) {
                int rl = mi * 16 + kq * 4 + j;
                rsum[wave][rl] = ps[mi][j];
                rsq[wave][rl]  = qs[mi][j];
            }
    }
    __syncthreads();
    float mean_a[4][4], rstd_a[4][4];
#pragma unroll
    for (int mi = 0; mi < 4; mi++)
#pragma unroll
        for (int j = 0; j < 4; j++) {
            int rl = mi * 16 + kq * 4 + j;
            float s  = rsum[0][rl] + rsum[1][rl] + rsum[2][rl] + rsum[3][rl];
            float s2 = rsq[0][rl] + rsq[1][rl] + rsq[2][rl] + rsq[3][rl];
            float mean = s * (1.f/256.f);
            float var  = s2 * (1.f/256.f) - mean * mean;
            mean_a[mi][j] = mean;
            rstd_a[mi][j] = rsqrtf(var + 1e-5f);
        }
#pragma unroll
    for (int mi = 0; mi < 4; mi++)
#pragma unroll
        for (int ni = 0; ni < 4; ni++) {
            int gcol = wave * 64 + ni * 16 + lr;
#pragma unroll
            for (int j = 0; j < 4; j++) {
                float m = (acc[mi][ni][j] - mean_a[mi][j]) * rstd_a[mi][j] * gv[ni] + b2v[ni];
                m_out[(size_t)srows[mi][j] * CC + gcol] = (f16)m;
            }
        }
}

// Fused MLP: out += fc2(gelu(fc1(m_in))); NO mh round-trip.
// fc1 operand-SWAPPED (A := w1, B := x); tanh-GELU in R10's expression shape
// with the precise division replaced by v_rcp (R15-validated: VGPR 124,
// VALU 40->29%). Bank-swizzled staging/reads this round; hbuf keeps its own
// swizzle. fc2: acc2 persistent across nb (K-loop accumulator).
__global__ __launch_bounds__(256) void k_mlp2(const f16* __restrict__ A,
                                              const f16* __restrict__ w1,
                                              const f16* __restrict__ w2,
                                              const float* __restrict__ fb1,
                                              const float* __restrict__ fb2,
                                              float* __restrict__ out) {
    __shared__ char sm[49152];
    char* hbuf = sm;                 // [64][128] f16, row stride 256B, XOR-swizzled
    char* S    = sm + 16384;         // 32KB: fc1 staging (As 8K + Bs1 16K) / fc2 Bs2 32K
    f16* As  = (f16*)S;              // [2][64*32]
    f16* Bs1 = (f16*)(S + 8192);     // [2][128*32]
    f16* Bs2 = (f16*)S;              // [2][256*32]
    const int tid = threadIdx.x, wave = tid >> 6, lane = tid & 63;
    const int lr = lane & 15, kq = lane >> 4;
    const int m0 = blockIdx.x * 64;
    const int ar = tid >> 2;
    const int ac = (((tid & 3) ^ ((tid >> 3) & 3))) * 8;   // swizzled source slot
    const int ksw = (kq ^ ((lr >> 1) & 3)) * 8;            // read slot

    f32x4 acc2[4][4];
#pragma unroll
    for (int i = 0; i < 4; i++)
#pragma unroll
        for (int j = 0; j < 4; j++) acc2[i][j] = f32x4{0.f, 0.f, 0.f, 0.f};

    for (int nb = 0; nb < 8; nb++) {
        auto stage1 = [&](int b, int k0) {
            gload16(&As[b * 2048 + wave * 512], &A[(size_t)(m0 + ar) * CC + k0 + ac]);
            gload16(&Bs1[b * 4096 + wave * 512],
                    &w1[(size_t)(nb * 128 + ar) * CC + k0 + ac]);
            gload16(&Bs1[b * 4096 + 2048 + wave * 512],
                    &w1[(size_t)(nb * 128 + 64 + ar) * CC + k0 + ac]);
        };
        // ---- fc1 slice (swapped): acc1[hid frags][q frags] ----
        f32x4 acc1[2][4];
#pragma unroll
        for (int i = 0; i < 2; i++)
#pragma unroll
            for (int j = 0; j < 4; j++) acc1[i][j] = f32x4{0.f, 0.f, 0.f, 0.f};
        stage1(0, 0);
        __syncthreads();
#pragma unroll
        for (int ks = 0; ks < 8; ks++) {
            int cur = ks & 1;
            if (ks + 1 < 8) stage1(cur ^ 1, (ks + 1) * 32);
            f16x8 aw1[2], bx[4];
#pragma unroll
            for (int hi = 0; hi < 2; hi++)
                aw1[hi] = *(const f16x8*)(&Bs1[cur * 4096 +
                                               (wave * 32 + hi * 16 + lr) * 32 + ksw]);
#pragma unroll
            for (int qi = 0; qi < 4; qi++)
                bx[qi] = *(const f16x8*)(&As[cur * 2048 + (qi * 16 + lr) * 32 + ksw]);
#pragma unroll
            for (int hi = 0; hi < 2; hi++)
#pragma unroll
                for (int qi = 0; qi < 4; qi++)
                    acc1[hi][qi] = __builtin_amdgcn_mfma_f32_16x16x32_f16(
                        aw1[hi], bx[qi], acc1[hi][qi], 0, 0, 0);
            __syncthreads();
        }
        // ---- gelu -> h (vectorized uint2, swizzled), stage fc2 B after ----
#pragma unroll
        for (int hi = 0; hi < 2; hi++) {
            float4 bb4 = *(const float4*)&fb1[nb * 128 + wave * 32 + hi * 16 + kq * 4];
            const float bb[4] = {bb4.x, bb4.y, bb4.z, bb4.w};
            const int hidb = wave * 64 + hi * 32 + kq * 8;   // byte = 2*hid base
#pragma unroll
            for (int qi = 0; qi < 4; qi++) {
                f16 t4[4];
#pragma unroll
                for (int j = 0; j < 4; j++) {
                    float v = acc1[hi][qi][j] + bb[j];
                    float z = 0.7978845608028654f * (v + 0.044715f * v * v * v);
                    float t = 1.f - 2.f * __builtin_amdgcn_rcpf(__expf(2.f * z) + 1.f);
                    t4[j] = (f16)(0.5f * v * (1.f + t));
                }
                int qrow = qi * 16 + lr;
                *(uint2*)(hbuf + qrow * 256 + (hidb ^ ((qrow & 7) << 4))) =
                    *(const uint2*)t4;
            }
        }
        auto stage2 = [&](int b, int k0) {
#pragma unroll
            for (int t = 0; t < 4; t++)
                gload16(&Bs2[b * 8192 + t * 2048 + wave * 512],
                        &w2[(size_t)(t * 64 + ar) * 1024 + nb * 128 + k0 + ac]);
        };
        stage2(0, 0);
        __syncthreads();     // h visible + Bs2[0] landed (barrier drains vmcnt)
        // ---- fc2 partial: acc2[64 q rows][wave's 64 out cols] += h @ w2_nb^T ----
#pragma unroll
        for (int ks = 0; ks < 4; ks++) {
            int cur = ks & 1;
            if (ks + 1 < 4) stage2(cur ^ 1, (ks + 1) * 32);
            f16x8 ah[4], bw[4];
#pragma unroll
            for (int mi = 0; mi < 4; mi++) {
                int row = mi * 16 + lr;
                ah[mi] = *(const f16x8*)(hbuf + row * 256 +
                                         ((ks * 64 + kq * 16) ^ ((row & 7) << 4)));
            }
#pragma unroll
            for (int ni = 0; ni < 4; ni++)
                bw[ni] = *(const f16x8*)(&Bs2[cur * 8192 +
                                              (wave * 64 + ni * 16 + lr) * 32 + ksw]);
#pragma unroll
            for (int mi = 0; mi < 4; mi++)
#pragma unroll
                for (int ni = 0; ni < 4; ni++)
                    acc2[mi][ni] = __builtin_amdgcn_mfma_f32_16x16x32_f16(
                        ah[mi], bw[ni], acc2[mi][ni], 0, 0, 0);
            __syncthreads();
        }
    }

    // ---- epilogue: out += acc2 + fb2 (coalesced 64B f32 segments) ----
#pragma unroll
    for (int mi = 0; mi < 4; mi++)
#pragma unroll
        for (int ni = 0; ni < 4; ni++)
#pragma unroll
            for (int j = 0; j < 4; j++) {
                int qrow = m0 + mi * 16 + kq * 4 + j;
                int oc = wave * 64 + ni * 16 + lr;
                size_t idx = (size_t)qrow * CC + oc;
                out[idx] = out[idx] + acc2[mi][ni][j] + fb2[oc];
            }
}

// MFMA attention: one wave per (window, head). S^T = mfma(K,Q); in-register
// softmax over keys; j-packed b64 swizzled LDS P-transpose; O^T = mfma(V^T, P);
// swizzled O-transpose -> 4 coalesced stores. 17.3KB LDS.
__global__ __launch_bounds__(64) void k_attn(const f16* __restrict__ q,
                                             const f16* __restrict__ kk,
                                             const f16* __restrict__ vv,
                                             const float* __restrict__ rpb,
                                             f16* __restrict__ aw, int winbase) {
    __shared__ char sm[17408];      // P[64][64] 8KB | VT[32][64] 4KB | O[64][32] 4KB | rl 900B
    float* rl = (float*)(sm + 16384);
    const int wl = blockIdx.x >> 3, h = blockIdx.x & 7;
    const int lane = threadIdx.x;
    const int lr = lane & 15, kq = lane >> 4;
    const size_t base = ((size_t)wl * 8 + h) * 2048;

    for (int i = lane; i < 225; i += 64) rl[i] = rpb[i * 8 + h];

    {
        f16 vr[32];
        const uint4* vs = (const uint4*)(vv + base + lane * 32);
#pragma unroll
        for (int c = 0; c < 4; c++) *(uint4*)&vr[c * 8] = vs[c];
#pragma unroll
        for (int d = 0; d < 32; d++)
            *(f16*)(sm + 8192 + d * 128 + ((lane * 2) ^ ((d & 7) << 4))) = vr[d];
    }

    f16x8 kf[4], qf[4];
#pragma unroll
    for (int t = 0; t < 4; t++) {
        kf[t] = *(const f16x8*)(kk + base + (size_t)(t * 16 + lr) * 32 + kq * 8);
        qf[t] = *(const f16x8*)(q  + base + (size_t)(t * 16 + lr) * 32 + kq * 8);
    }

    f32x4 st[4][4];
#pragma unroll
    for (int mi = 0; mi < 4; mi++)
#pragma unroll
        for (int ni = 0; ni < 4; ni++) st[mi][ni] = f32x4{0.f, 0.f, 0.f, 0.f};
#pragma unroll
    for (int mi = 0; mi < 4; mi++)
#pragma unroll
        for (int ni = 0; ni < 4; ni++)
            st[mi][ni] = __builtin_amdgcn_mfma_f32_16x16x32_f16(kf[mi], qf[ni], st[mi][ni], 0, 0, 0);

    __syncthreads();

    const int gwin = (winbase + wl) & 63;
    const int wh = gwin >> 3, ww = gwin & 7;
    int yq[4], xq[4], rq[4];
#pragma unroll
    for (int ni = 0; ni < 4; ni++) {
        int qq = ni * 16 + lr;
        yq[ni] = qq >> 3; xq[ni] = qq & 7;
        rq[ni] = ((wh < 7) ? 0 : ((yq[ni] < 4) ? 1 : 2)) * 3 +
                 ((ww < 7) ? 0 : ((xq[ni] < 4) ? 1 : 2));
    }
#pragma unroll
    for (int mi = 0; mi < 4; mi++)
#pragma unroll
        for (int j = 0; j < 4; j++) {
            int kt = mi * 16 + kq * 4 + j;
            int yk = kt >> 3, xk = kt & 7;
            int rk = ((wh < 7) ? 0 : ((yk < 4) ? 1 : 2)) * 3 +
                     ((ww < 7) ? 0 : ((xk < 4) ? 1 : 2));
#pragma unroll
            for (int ni = 0; ni < 4; ni++) {
                float b = rl[(yq[ni] - yk + 7) * 15 + (xq[ni] - xk + 7)];
                if (rq[ni] != rk) b -= 100.f;
                st[mi][ni][j] += b;
            }
        }

    float mx[4] = {-1e30f, -1e30f, -1e30f, -1e30f};
#pragma unroll
    for (int mi = 0; mi < 4; mi++)
#pragma unroll
        for (int ni = 0; ni < 4; ni++)
#pragma unroll
            for (int j = 0; j < 4; j++) mx[ni] = fmaxf(mx[ni], st[mi][ni][j]);
#pragma unroll
    for (int ni = 0; ni < 4; ni++) {
        mx[ni] = fmaxf(mx[ni], __shfl_xor(mx[ni], 16));
        mx[ni] = fmaxf(mx[ni], __shfl_xor(mx[ni], 32));
    }
    float sme[4] = {0.f, 0.f, 0.f, 0.f};
#pragma unroll
    for (int mi = 0; mi < 4; mi++)
#pragma unroll
        for (int ni = 0; ni < 4; ni++)
#pragma unroll
            for (int j = 0; j < 4; j++) {
                float e = __expf(st[mi][ni][j] - mx[ni]);
                st[mi][ni][j] = e;
                sme[ni] += e;
            }
#pragma unroll
    for (int ni = 0; ni < 4; ni++) {
        sme[ni] += __shfl_xor(sme[ni], 16);
        sme[ni] += __shfl_xor(sme[ni], 32);
    }
    float inv[4];
#pragma unroll
    for (int ni = 0; ni < 4; ni++) inv[ni] = 1.f / sme[ni];

#pragma unroll
    for (int mi = 0; mi < 4; mi++)
#pragma unroll
        for (int ni = 0; ni < 4; ni++) {
            f16 t4[4];
#pragma unroll
            for (int j = 0; j < 4; j++) t4[j] = (f16)st[mi][ni][j];
            int qq = ni * 16 + lr;
            *(uint2*)(sm + qq * 128 + ((mi * 32 + kq * 8) ^ ((qq & 7) << 4))) =
                *(const uint2*)t4;
        }
    __syncthreads();

    f32x4 oa[2][4];
#pragma unroll
    for (int mi2 = 0; mi2 < 2; mi2++)
#pragma unroll
        for (int ni = 0; ni < 4; ni++) oa[mi2][ni] = f32x4{0.f, 0.f, 0.f, 0.f};
#pragma unroll
    for (int ks = 0; ks < 2; ks++) {
        f16x8 va[2], pb[4];
#pragma unroll
        for (int mi2 = 0; mi2 < 2; mi2++) {
            int row = mi2 * 16 + lr;
            va[mi2] = *(const f16x8*)(sm + 8192 + row * 128 +
                                      ((ks * 64 + kq * 16) ^ ((row & 7) << 4)));
        }
#pragma unroll
        for (int ni = 0; ni < 4; ni++) {
            int qq = ni * 16 + lr;
            pb[ni] = *(const f16x8*)(sm + qq * 128 +
                                     ((ks * 64 + kq * 16) ^ ((qq & 7) << 4)));
        }
#pragma unroll
        for (int mi2 = 0; mi2 < 2; mi2++)
#pragma unroll
            for (int ni = 0; ni < 4; ni++)
                oa[mi2][ni] = __builtin_amdgcn_mfma_f32_16x16x32_f16(va[mi2], pb[ni], oa[mi2][ni], 0, 0, 0);
    }

#pragma unroll
    for (int mi2 = 0; mi2 < 2; mi2++)
#pragma unroll
        for (int ni = 0; ni < 4; ni++) {
            f16 t4[4];
#pragma unroll
            for (int j = 0; j < 4; j++) t4[j] = (f16)(oa[mi2][ni][j] * inv[ni]);
            int qq = ni * 16 + lr;
            *(uint2*)(sm + 12288 + qq * 64 + ((mi2 * 32 + kq * 8) ^ ((qq & 3) << 4))) =
                *(const uint2*)t4;
        }
    __syncthreads();

    f16* dst = aw + ((size_t)(wl * 64 + lane)) * CC + h * 32;
#pragma unroll
    for (int c = 0; c < 4; c++) {
        uint4 wv = *(const uint4*)(sm + 12288 + lane * 64 +
                                   ((c * 16) ^ ((lane & 3) << 4)));
        *(uint4*)(dst + c * 8) = wv;
    }
}

extern "C" void kernel_launch(void* const* d_in, const int* in_sizes, int n_in,
                              void* d_out, int out_size, void* d_ws, size_t ws_size,
                              hipStream_t stream) {
    (void)in_sizes; (void)n_in; (void)out_size; (void)ws_size;
    const float* x      = (const float*)d_in[0];
    const float* g1     = (const float*)d_in[1];
    const float* b1     = (const float*)d_in[2];
    const float* qkv_w  = (const float*)d_in[3];
    const float* qkv_b  = (const float*)d_in[4];
    const float* rpb    = (const float*)d_in[5];
    const float* proj_w = (const float*)d_in[6];
    const float* proj_b = (const float*)d_in[7];
    const float* g2     = (const float*)d_in[8];
    const float* b2     = (const float*)d_in[9];
    const float* fc1_w  = (const float*)d_in[10];
    const float* fc1_b  = (const float*)d_in[11];
    const float* fc2_w  = (const float*)d_in[12];
    const float* fc2_b  = (const float*)d_in[13];
    float* out = (float*)d_out;
    char* ws = (char*)d_ws;
    f16* wq = (f16*)(ws + OFF_WQ);
    f16* wp = (f16*)(ws + OFF_WP);
    f16* w1 = (f16*)(ws + OFF_W1);
    f16* w2 = (f16*)(ws + OFF_W2);
    f16* awb = (f16*)(ws + OFF_R1);
    static constexpr size_t QSZ = (size_t)CWINS * 8 * 64 * 32 * 2; // 16,777,216 B
    f16* hwin = (f16*)(ws + OFF_R2);
    f16* qb   = (f16*)(ws + OFF_R2 + QSZ);
    f16* kb   = (f16*)(ws + OFF_R2 + 2 * QSZ);
    f16* vb   = (f16*)(ws + OFF_R2 + 3 * QSZ);
    f16* m_in = (f16*)(ws + OFF_R2);

    k_cvt<<<768, 256, 0, stream>>>(qkv_w, wq, 768 * 256);
    k_cvt<<<256, 256, 0, stream>>>(proj_w, wp, 256 * 256);
    k_cvt<<<1024, 256, 0, stream>>>(fc1_w, w1, 1024 * 256);
    k_cvt<<<1024, 256, 0, stream>>>(fc2_w, w2, 1024 * 256);

    // --- attention phase: per chunk LN1 -> QKV -> attn (writes full AW) ---
    for (int c = 0; c < ACH; c++) {
        k_ln<<<AROWS / 4, 256, 0, stream>>>(x, g1, b1, hwin, c * AROWS);
        k_qkv<<<dim3(AROWS / 128, 6), 256, 0, stream>>>(
            hwin, wq, qkv_b, qb, kb, vb);
        k_attn<<<CWINS * 8, 64, 0, stream>>>(
            qb, kb, vb, rpb, awb + (size_t)c * AROWS * CC, c * CWINS);
    }
    // proj over full M, fused un-shift + residual -> out, fused LN2 -> m_in
    k_proj<<<ROWS / 64, 256, 0, stream>>>(awb, wp, proj_b, x, out, m_in, g2, b2);

    // --- fused MLP (no mh round-trip), single launch over full M ---
    k_mlp2<<<ROWS / 64, 256, 0, stream>>>(m_in, w1, w2, fc1_b, fc2_b, out);
}